// Round 7
// baseline (3678.653 us; speedup 1.0000x reference)
//
#include <hip/hip_runtime.h>
#include <math.h>

#define B 16
#define N 1024
#define KNB 20

typedef unsigned int u32;
typedef unsigned long long u64;

__device__ __forceinline__ float sgnf(float v) {
    return (v > 0.f) ? 1.f : ((v < 0.f) ? -1.f : 0.f);
}

__global__ __launch_bounds__(256) void sentinel_kernel(float* __restrict__ out, int n, float v) {
    int i = blockIdx.x * blockDim.x + threadIdx.x;
    if (i < n) out[i] = v;
}

// ---------------- np-exact sq (UNCHANGED arithmetic) ----------------

template <int C>
__global__ __launch_bounds__(256) void sq_np_kernel(const float* __restrict__ x, int Ctot, int c0,
                                                    float* __restrict__ sq) {
    int i = blockIdx.x * blockDim.x + threadIdx.x;
    if (i >= B * N) return;
    int b = i >> 10, n = i & (N - 1);
    const float* xb = x + ((size_t)b * Ctot + c0) * N + n;
    float res;
    if (C < 8) {
        float v0 = xb[0];
        res = __fmul_rn(v0, v0);
        for (int c = 1; c < C; ++c) {
            float v = xb[(size_t)c * N];
            res = __fadd_rn(res, __fmul_rn(v, v));
        }
    } else {
        float r[8];
#pragma unroll
        for (int j = 0; j < 8; ++j) {
            float v = xb[(size_t)j * N];
            r[j] = __fmul_rn(v, v);
        }
        for (int c = 8; c < C; c += 8) {
#pragma unroll
            for (int j = 0; j < 8; ++j) {
                float v = xb[(size_t)(c + j) * N];
                r[j] = __fadd_rn(r[j], __fmul_rn(v, v));
            }
        }
        res = __fadd_rn(__fadd_rn(__fadd_rn(r[0], r[1]), __fadd_rn(r[2], r[3])),
                        __fadd_rn(__fadd_rn(r[4], r[5]), __fadd_rn(r[6], r[7])));
    }
    sq[i] = res;
}

// ---------------- transpose to row-major xT[(b*N+n)*C + c] ----------------

__global__ __launch_bounds__(256) void transpose_kernel(const float* __restrict__ x, int Ctot,
                                                        int c0, int C, float* __restrict__ xT) {
    const int nb = blockIdx.x * 64, cb = blockIdx.y * 64, b = blockIdx.z;
    const int tid = threadIdx.x;
    __shared__ float t[64][65];
    for (int i = tid; i < 64 * 64; i += 256) {
        int cc = i >> 6, nn = i & 63;
        t[cc][nn] = x[((size_t)b * Ctot + c0 + cb + cc) * N + nb + nn];
    }
    __syncthreads();
    for (int i = tid; i < 64 * 64; i += 256) {
        int nn = i >> 6, cc = i & 63;
        xT[((size_t)b * N + nb + nn) * C + cb + cc] = t[cc][nn];
    }
}

__global__ __launch_bounds__(256) void transpose3_kernel(const float* __restrict__ x,
                                                         float* __restrict__ xT) {
    int i = blockIdx.x * blockDim.x + threadIdx.x;
    if (i >= B * N) return;
    int b = i >> 10, n = i & (N - 1);
    xT[(size_t)i * 3 + 0] = x[((size_t)b * 3 + 0) * N + n];
    xT[(size_t)i * 3 + 1] = x[((size_t)b * 3 + 1) * N + n];
    xT[(size_t)i * 3 + 2] = x[((size_t)b * 3 + 2) * N + n];
}

// ---------------- fast knn: reg-resident distances + barrier-free wave top-k ----------------
// Same np-exact arithmetic per (n,m): ascending-c mul_rn/add_rn chain, ((2a-sqn)-sqm).
// Selection: per-wave stable top-20 via shfl butterfly (lexicographic max on (v, -i)),
// then stable 4-way merge -> identical result to global stable top-20.
template <int C>
__global__ __launch_bounds__(256) void knn_fast_kernel(const float* __restrict__ xT,
                                                       const float* __restrict__ sq,
                                                       int* __restrict__ idxout) {
    const int b = blockIdx.y, n = blockIdx.x, tid = threadIdx.x;
    const int wave = tid >> 6, lane = tid & 63;
    __shared__ float xn[(C < 4) ? 4 : C];
    __shared__ float mv[4][KNB];
    __shared__ int mi[4][KNB];
    const float* xb = xT + (size_t)b * N * C;
    if ((C % 4) == 0) {
        for (int t = tid; t < C / 4; t += 256)
            reinterpret_cast<float4*>(xn)[t] =
                reinterpret_cast<const float4*>(xb + (size_t)n * C)[t];
    } else {
        if (tid < C) xn[tid] = xb[(size_t)n * C + tid];
    }
    __syncthreads();
    const float sqn = sq[b * N + n];
    const int mbase = wave * 256 + lane * 4;
    const float* rp = xb + (size_t)mbase * C;
    float acc0 = 0.f, acc1 = 0.f, acc2 = 0.f, acc3 = 0.f;
    if ((C % 4) == 0) {
        for (int c = 0; c < C; c += 4) {
            float4 xv = *reinterpret_cast<const float4*>(xn + c);
            float4 r0 = *reinterpret_cast<const float4*>(rp + c);
            float4 r1 = *reinterpret_cast<const float4*>(rp + C + c);
            float4 r2 = *reinterpret_cast<const float4*>(rp + 2 * C + c);
            float4 r3 = *reinterpret_cast<const float4*>(rp + 3 * C + c);
            acc0 = __fadd_rn(acc0, __fmul_rn(xv.x, r0.x));
            acc0 = __fadd_rn(acc0, __fmul_rn(xv.y, r0.y));
            acc0 = __fadd_rn(acc0, __fmul_rn(xv.z, r0.z));
            acc0 = __fadd_rn(acc0, __fmul_rn(xv.w, r0.w));
            acc1 = __fadd_rn(acc1, __fmul_rn(xv.x, r1.x));
            acc1 = __fadd_rn(acc1, __fmul_rn(xv.y, r1.y));
            acc1 = __fadd_rn(acc1, __fmul_rn(xv.z, r1.z));
            acc1 = __fadd_rn(acc1, __fmul_rn(xv.w, r1.w));
            acc2 = __fadd_rn(acc2, __fmul_rn(xv.x, r2.x));
            acc2 = __fadd_rn(acc2, __fmul_rn(xv.y, r2.y));
            acc2 = __fadd_rn(acc2, __fmul_rn(xv.z, r2.z));
            acc2 = __fadd_rn(acc2, __fmul_rn(xv.w, r2.w));
            acc3 = __fadd_rn(acc3, __fmul_rn(xv.x, r3.x));
            acc3 = __fadd_rn(acc3, __fmul_rn(xv.y, r3.y));
            acc3 = __fadd_rn(acc3, __fmul_rn(xv.z, r3.z));
            acc3 = __fadd_rn(acc3, __fmul_rn(xv.w, r3.w));
        }
    } else {
        for (int c = 0; c < C; ++c) {
            float xv = xn[c];
            acc0 = __fadd_rn(acc0, __fmul_rn(xv, rp[c]));
            acc1 = __fadd_rn(acc1, __fmul_rn(xv, rp[C + c]));
            acc2 = __fadd_rn(acc2, __fmul_rn(xv, rp[2 * C + c]));
            acc3 = __fadd_rn(acc3, __fmul_rn(xv, rp[3 * C + c]));
        }
    }
    float dv[4];
    dv[0] = __fsub_rn(__fsub_rn(__fmul_rn(2.f, acc0), sqn), sq[b * N + mbase + 0]);
    dv[1] = __fsub_rn(__fsub_rn(__fmul_rn(2.f, acc1), sqn), sq[b * N + mbase + 1]);
    dv[2] = __fsub_rn(__fsub_rn(__fmul_rn(2.f, acc2), sqn), sq[b * N + mbase + 2]);
    dv[3] = __fsub_rn(__fsub_rn(__fmul_rn(2.f, acc3), sqn), sq[b * N + mbase + 3]);
    // per-wave stable top-20 (no barriers)
    for (int kk = 0; kk < KNB; ++kk) {
        float bv = dv[0];
        int bi = mbase;
        if (dv[1] > bv) { bv = dv[1]; bi = mbase + 1; }
        if (dv[2] > bv) { bv = dv[2]; bi = mbase + 2; }
        if (dv[3] > bv) { bv = dv[3]; bi = mbase + 3; }
#pragma unroll
        for (int off = 1; off < 64; off <<= 1) {
            float ov = __shfl_xor(bv, off);
            int oi = __shfl_xor(bi, off);
            if (ov > bv || (ov == bv && oi < bi)) { bv = ov; bi = oi; }
        }
        if (lane == 0) { mv[wave][kk] = bv; mi[wave][kk] = bi; }
        int lj = bi - mbase;
        if (lj >= 0 && lj < 4) dv[lj] = -3.4e38f;
    }
    __syncthreads();
    // stable 4-way merge (wave ranges have ascending disjoint indices)
    if (tid == 0) {
        int* out = idxout + ((size_t)b * N + n) * KNB;
        int p0 = 0, p1 = 0, p2 = 0, p3 = 0;
        for (int kk = 0; kk < KNB; ++kk) {
            float h0 = (p0 < KNB) ? mv[0][p0] : -3.4e38f;
            float h1 = (p1 < KNB) ? mv[1][p1] : -3.4e38f;
            float h2 = (p2 < KNB) ? mv[2][p2] : -3.4e38f;
            float h3 = (p3 < KNB) ? mv[3][p3] : -3.4e38f;
            float bv = h0;
            int bw = 0;
            if (h1 > bv) { bv = h1; bw = 1; }
            if (h2 > bv) { bv = h2; bw = 2; }
            if (h3 > bv) { bv = h3; bw = 3; }
            if (bw == 0) out[kk] = mi[0][p0++];
            else if (bw == 1) out[kk] = mi[1][p1++];
            else if (bw == 2) out[kk] = mi[2][p2++];
            else out[kk] = mi[3][p3++];
        }
    }
}

// ---------------- layer-1 edgeconv (np-exact, UNCHANGED) ----------------

template <int C, int COUT>
__global__ __launch_bounds__(COUT) void edgeconv1_kernel(
    const float* __restrict__ xin, int Ctot_in, int c0_in, const int* __restrict__ idx,
    const float* __restrict__ W, const float* __restrict__ aa, const float* __restrict__ ssc,
    const float* __restrict__ bbi, const float* __restrict__ pp, float* __restrict__ xout,
    int c0_out) {
    const int b = blockIdx.y, n = blockIdx.x, tid = threadIdx.x;
    __shared__ float ctr_raw[C];
    __shared__ float ctr_f[C];
    __shared__ __align__(16) float df[C][KNB];
    __shared__ int ids[KNB];
    const float* xb = xin + ((size_t)b * Ctot_in + c0_in) * N;
    if (tid < KNB) ids[tid] = idx[((size_t)b * N + n) * KNB + tid];
    for (int c = tid; c < C; c += COUT) {
        float v = xb[(size_t)c * N + n];
        ctr_raw[c] = v;
        ctr_f[c] = v;
    }
    __syncthreads();
    for (int t = tid; t < C * KNB; t += COUT) {
        int c = t / KNB, k = t - c * KNB;
        df[c][k] = __fsub_rn(xb[(size_t)c * N + ids[k]], ctr_raw[c]);
    }
    __syncthreads();
    const int o = tid;
    const float* wrow = W + (size_t)o * (2 * C);
    const float as = __fmul_rn(aa[o], ssc[o]);
    const float bo = bbi[o], po = pp[o];
    float best = -3.4e38f;
    float wd[C], wc[C];
    for (int c = 0; c < C; ++c) { wd[c] = sgnf(wrow[c]); wc[c] = sgnf(wrow[C + c]); }
    for (int k = 0; k < KNB; ++k) {
        float acc = 0.f;
        for (int c = 0; c < C; ++c) acc = __fadd_rn(acc, __fmul_rn(df[c][k], wd[c]));
        for (int c = 0; c < C; ++c) acc = __fadd_rn(acc, __fmul_rn(ctr_f[c], wc[c]));
        float y = __fadd_rn(__fmul_rn(acc, as), bo);
        y = y > 0.f ? y : __fmul_rn(po, y);
        best = fmaxf(best, y);
    }
    xout[((size_t)b * 512 + (c0_out + o)) * N + n] = best;
}

// ---------------- ternary bitpack helpers ----------------

__global__ __launch_bounds__(256) void pack_rows_kernel(const float* __restrict__ src, int rows,
                                                        int cols, u32* __restrict__ s,
                                                        u32* __restrict__ nz) {
    int i = blockIdx.x * blockDim.x + threadIdx.x;
    int wpr = cols >> 5;
    if (i >= rows * wpr) return;
    int r = i / wpr, w = i - r * wpr;
    const float* p = src + (size_t)r * cols + (size_t)w * 32;
    u32 sb = 0, nb = 0;
    for (int j = 0; j < 32; ++j) {
        float v = p[j];
        if (v < 0.f) sb |= (1u << j);
        if (v != 0.f) nb |= (1u << j);
    }
    s[i] = sb;
    nz[i] = nb;
}

__global__ __launch_bounds__(256) void pack_cols_kernel(const float* __restrict__ x,
                                                        u32* __restrict__ s,
                                                        u32* __restrict__ nz) {
    int i = blockIdx.x * blockDim.x + threadIdx.x;
    if (i >= B * 16 * N) return;
    int n = i & (N - 1);
    int w = (i >> 10) & 15;
    int b = i >> 14;
    const float* p = x + ((size_t)b * 512 + (size_t)w * 32) * N + n;
    u32 sb = 0, nb = 0;
    for (int j = 0; j < 32; ++j) {
        float v = p[(size_t)j * N];
        if (v < 0.f) sb |= (1u << j);
        if (v != 0.f) nb |= (1u << j);
    }
    s[i] = sb;
    nz[i] = nb;
}

// ---------------- binarized edgeconv via xor/popcount (exact integer) ----------------

template <int C, int COUT>
__global__ __launch_bounds__(COUT) void edgeconv_bin_kernel(
    const float* __restrict__ xin, int Ctot_in, int c0_in, const int* __restrict__ idx,
    const u32* __restrict__ wsm, const u32* __restrict__ wnzm, const float* __restrict__ aa,
    const float* __restrict__ ssc, const float* __restrict__ bbi, const float* __restrict__ pp,
    float* __restrict__ xout, int c0_out) {
    constexpr int W = C / 32;
    const int b = blockIdx.y, n = blockIdx.x, tid = threadIdx.x;
    __shared__ float ctr_raw[C];
    __shared__ int ids[KNB];
    __shared__ u32 ctr_s[W], ctr_nz[W];
    __shared__ u32 dfs[KNB][W], dfnz[KNB][W];
    const float* xb = xin + ((size_t)b * Ctot_in + c0_in) * N;
    if (tid < KNB) ids[tid] = idx[((size_t)b * N + n) * KNB + tid];
    if (tid < C) {
        float v = xb[(size_t)tid * N + n];
        ctr_raw[tid] = v;
        u64 bs = __ballot(v < 0.f);
        u64 bnz = __ballot(v != 0.f);
        if ((tid & 63) == 0) {
            int wb = tid >> 5;
            ctr_s[wb] = (u32)bs;       ctr_s[wb + 1] = (u32)(bs >> 32);
            ctr_nz[wb] = (u32)bnz;     ctr_nz[wb + 1] = (u32)(bnz >> 32);
        }
    }
    __syncthreads();
    for (int t = tid; t < KNB * C; t += COUT) {
        int k = t / C, c = t - k * C;
        float v = __fsub_rn(xb[(size_t)c * N + ids[k]], ctr_raw[c]);
        u64 bs = __ballot(v < 0.f);
        u64 bnz = __ballot(v != 0.f);
        if ((c & 63) == 0) {
            int wb = c >> 5;
            dfs[k][wb] = (u32)bs;      dfs[k][wb + 1] = (u32)(bs >> 32);
            dfnz[k][wb] = (u32)bnz;    dfnz[k][wb + 1] = (u32)(bnz >> 32);
        }
    }
    __syncthreads();
    const int o = tid;
    const u32* wsrow = wsm + (size_t)o * 2 * W;
    const u32* wnzrow = wnzm + (size_t)o * 2 * W;
    u32 wds[W], wdnz[W], wcs[W], wcnz[W];
#pragma unroll
    for (int w = 0; w < W; ++w) {
        wds[w] = wsrow[w];      wcs[w] = wsrow[W + w];
        wdnz[w] = wnzrow[w];    wcnz[w] = wnzrow[W + w];
    }
    int cdot = 0;
#pragma unroll
    for (int w = 0; w < W; ++w) {
        u32 nzb = ctr_nz[w] & wcnz[w];
        u32 neg = (ctr_s[w] ^ wcs[w]) & nzb;
        cdot += __popc(nzb) - 2 * __popc(neg);
    }
    const float as = __fmul_rn(aa[o], ssc[o]);
    const float bo = bbi[o], po = pp[o];
    float best = -3.4e38f;
    for (int k = 0; k < KNB; ++k) {
        int dot = cdot;
#pragma unroll
        for (int w = 0; w < W; ++w) {
            u32 nzb = dfnz[k][w] & wdnz[w];
            u32 neg = (dfs[k][w] ^ wds[w]) & nzb;
            dot += __popc(nzb) - 2 * __popc(neg);
        }
        float y = __fadd_rn(__fmul_rn((float)dot, as), bo);
        y = y > 0.f ? y : __fmul_rn(po, y);
        best = fmaxf(best, y);
    }
    xout[((size_t)b * 512 + (c0_out + o)) * N + n] = best;
}

// ---------------- conv1d bitplane popcount + fused pooling ----------------

__global__ __launch_bounds__(256) void conv1d_bin_pool_kernel(
    const u32* __restrict__ xs, const u32* __restrict__ xnz, const u32* __restrict__ w5s,
    const u32* __restrict__ w5nz, const float* __restrict__ aa, const float* __restrict__ ssc,
    const float* __restrict__ bbi, const float* __restrict__ pp, float* __restrict__ pmax,
    float* __restrict__ psum) {
    const int b = blockIdx.y;
    const int otile = blockIdx.x & 3;
    const int nq = blockIdx.x >> 2;
    const int tid = threadIdx.x;
    const int o = otile * 256 + tid;
    __shared__ u32 shs[128][20];
    __shared__ u32 shnz[128][20];
    u32 ws[16], wnz[16];
#pragma unroll
    for (int w = 0; w < 16; ++w) {
        ws[w] = w5s[(size_t)o * 16 + w];
        wnz[w] = w5nz[(size_t)o * 16 + w];
    }
    const float as = __fmul_rn(aa[o], ssc[o]);
    const float bo = bbi[o], po = pp[o];
    float m = -3.4e38f, sum = 0.f;
    for (int half = 0; half < 2; ++half) {
        const int nbase = nq * 256 + half * 128;
        __syncthreads();
        for (int t = tid; t < 16 * 128; t += 256) {
            int w = t >> 7, nl = t & 127;
            shs[nl][w] = xs[((size_t)b * 16 + w) * N + nbase + nl];
            shnz[nl][w] = xnz[((size_t)b * 16 + w) * N + nbase + nl];
        }
        __syncthreads();
        for (int nl = 0; nl < 128; ++nl) {
            int dot = 0;
#pragma unroll
            for (int w = 0; w < 16; ++w) {
                u32 nzb = shnz[nl][w] & wnz[w];
                u32 neg = (shs[nl][w] ^ ws[w]) & nzb;
                dot += __popc(nzb) - 2 * __popc(neg);
            }
            float y = __fadd_rn(__fmul_rn((float)dot, as), bo);
            y = y > 0.f ? y : __fmul_rn(po, y);
            m = fmaxf(m, y);
            sum = __fadd_rn(sum, y);
        }
    }
    pmax[((size_t)b * 1024 + o) * 4 + nq] = m;
    psum[((size_t)b * 1024 + o) * 4 + nq] = sum;
}

__global__ __launch_bounds__(256) void pool_reduce_kernel(const float* __restrict__ pmax,
                                                          const float* __restrict__ psum,
                                                          float* __restrict__ pooled) {
    int i = blockIdx.x * blockDim.x + threadIdx.x;
    if (i >= B * 1024) return;
    int b = i >> 10, o = i & 1023;
    const float* pm = pmax + (size_t)i * 4;
    const float* ps = psum + (size_t)i * 4;
    float m = -3.4e38f, s = 0.f;
    for (int t = 0; t < 4; ++t) { m = fmaxf(m, pm[t]); s = __fadd_rn(s, ps[t]); }
    pooled[(size_t)b * 2048 + o] = m;
    pooled[(size_t)b * 2048 + 1024 + o] = __fmul_rn(s, (1.f / 1024.f));
}

// ---------------- heads (UNCHANGED) ----------------

__global__ __launch_bounds__(512) void lin1_kernel(const float* __restrict__ xin,
                                                   const float* __restrict__ W,
                                                   const float* __restrict__ aa,
                                                   const float* __restrict__ ssc,
                                                   const float* __restrict__ bbi,
                                                   const float* __restrict__ pp,
                                                   float* __restrict__ out) {
    int b = blockIdx.x, tid = threadIdx.x;
    __shared__ float sx[2048];
    for (int c = tid; c < 2048; c += 512) sx[c] = sgnf(xin[b * 2048 + c]);
    __syncthreads();
    int o = tid;
    const float* wrow = W + (size_t)o * 2048;
    float acc = 0.f;
    for (int c = 0; c < 2048; ++c) acc = fmaf(sx[c], sgnf(wrow[c]), acc);
    float y = __fadd_rn(__fmul_rn(acc, __fmul_rn(aa[o], ssc[o])), bbi[o]);
    out[b * 512 + o] = y > 0.f ? y : __fmul_rn(pp[o], y);
}

__global__ __launch_bounds__(256) void lin2_kernel(const float* __restrict__ xin,
                                                   const float* __restrict__ W,
                                                   const float* __restrict__ aa,
                                                   const float* __restrict__ ssc,
                                                   const float* __restrict__ bbi,
                                                   const float* __restrict__ pp,
                                                   float* __restrict__ out) {
    int b = blockIdx.x, tid = threadIdx.x;
    __shared__ float sx[512];
    for (int c = tid; c < 512; c += 256) sx[c] = sgnf(xin[b * 512 + c]);
    __syncthreads();
    int o = tid;
    const float* wrow = W + (size_t)o * 512;
    float acc = 0.f;
    for (int c = 0; c < 512; ++c) acc = fmaf(sx[c], sgnf(wrow[c]), acc);
    float y = __fadd_rn(__fmul_rn(acc, __fmul_rn(aa[o], ssc[o])), bbi[o]);
    out[b * 256 + o] = y > 0.f ? y : __fmul_rn(pp[o], y);
}

__global__ __launch_bounds__(64) void lin3_kernel(const float* __restrict__ xin,
                                                  const float* __restrict__ W,
                                                  const float* __restrict__ ssc,
                                                  const float* __restrict__ bbi,
                                                  float* __restrict__ out) {
    int b = blockIdx.x, j = threadIdx.x;
    if (j >= 40) return;
    const float* wrow = W + j * 256;
    const float* xb = xin + b * 256;
    double acc = 0.0;
    for (int c = 0; c < 256; ++c) acc = fma((double)xb[c], (double)wrow[c], acc);
    out[b * 40 + j] = __fadd_rn(__fmul_rn((float)acc, ssc[j]), bbi[j]);
}

extern "C" void kernel_launch(void* const* d_in, const int* in_sizes, int n_in, void* d_out,
                              int out_size, void* d_ws, size_t ws_size, hipStream_t stream) {
    float* outp = (float*)d_out;
    auto sentinel = [&](float code) {
        sentinel_kernel<<<(640 + 255) / 256, 256, 0, stream>>>(outp, 640, code * 1.0e6f);
    };
    if (n_in != 39) { sentinel(1.f); return; }
    static const int expect[39] = {
        16 * 3 * 1024,
        64 * 6, 64, 64, 64, 64,
        64 * 128, 64, 64, 64, 64,
        128 * 128, 128, 128, 128, 128,
        256 * 256, 256, 256, 256, 256,
        1024 * 512, 1024, 1024, 1024, 1024,
        512 * 2048, 512, 512, 512, 512,
        256 * 512, 256, 256, 256, 256,
        40 * 256, 40, 40
    };
    for (int i = 0; i < 39; ++i)
        if (in_sizes[i] != expect[i]) { sentinel(2.f); return; }
    if (out_size != 640) { sentinel(3.f); return; }

    const float* x0 = (const float*)d_in[0];
    const float *w1 = (const float*)d_in[1], *a1 = (const float*)d_in[2],
                *s1 = (const float*)d_in[3], *b1 = (const float*)d_in[4],
                *p1 = (const float*)d_in[5];
    const float *a2 = (const float*)d_in[7], *s2 = (const float*)d_in[8],
                *b2 = (const float*)d_in[9], *p2 = (const float*)d_in[10];
    const float *a3 = (const float*)d_in[12], *s3 = (const float*)d_in[13],
                *b3 = (const float*)d_in[14], *p3 = (const float*)d_in[15];
    const float *a4 = (const float*)d_in[17], *s4 = (const float*)d_in[18],
                *b4 = (const float*)d_in[19], *p4 = (const float*)d_in[20];
    const float *a5 = (const float*)d_in[22], *s5 = (const float*)d_in[23],
                *b5 = (const float*)d_in[24], *p5 = (const float*)d_in[25];
    const float *w2 = (const float*)d_in[6], *w3 = (const float*)d_in[11],
                *w4 = (const float*)d_in[16], *w5 = (const float*)d_in[21];
    const float *wl1 = (const float*)d_in[26], *al1 = (const float*)d_in[27],
                *sl1 = (const float*)d_in[28], *bl1 = (const float*)d_in[29],
                *pl1 = (const float*)d_in[30];
    const float *wl2 = (const float*)d_in[31], *al2 = (const float*)d_in[32],
                *sl2 = (const float*)d_in[33], *bl2 = (const float*)d_in[34],
                *pl2 = (const float*)d_in[35];
    const float *wl3 = (const float*)d_in[36], *sl3 = (const float*)d_in[37],
                *bl3 = (const float*)d_in[38];

    char* ws = (char*)d_ws;
    size_t off = 0;
    auto alloc = [&](size_t bytes) -> void* {
        void* p = ws + off;
        off += (bytes + 255) & ~(size_t)255;
        return p;
    };
    float* xcat = (float*)alloc((size_t)B * 512 * N * 4);
    float* xT = (float*)alloc((size_t)B * N * 128 * 4);   // transposed panel (max C=128)
    int* idxb = (int*)alloc((size_t)B * N * KNB * 4);
    float* sqb = (float*)alloc((size_t)B * N * 4);
    u32* w2s_ = (u32*)alloc(64 * 4 * 4);     u32* w2nz_ = (u32*)alloc(64 * 4 * 4);
    u32* w3s_ = (u32*)alloc(128 * 4 * 4);    u32* w3nz_ = (u32*)alloc(128 * 4 * 4);
    u32* w4s_ = (u32*)alloc(256 * 8 * 4);    u32* w4nz_ = (u32*)alloc(256 * 8 * 4);
    u32* w5s_ = (u32*)alloc(1024 * 16 * 4);  u32* w5nz_ = (u32*)alloc(1024 * 16 * 4);
    u32* xss = (u32*)alloc((size_t)B * 16 * N * 4);
    u32* xnzs = (u32*)alloc((size_t)B * 16 * N * 4);
    float* pmax = (float*)alloc((size_t)B * 1024 * 4 * 4);
    float* psum = (float*)alloc((size_t)B * 1024 * 4 * 4);
    float* pooled = (float*)alloc((size_t)B * 2048 * 4);
    float* l1o = (float*)alloc((size_t)B * 512 * 4);
    float* l2o = (float*)alloc((size_t)B * 256 * 4);
    if (off > ws_size) { sentinel(4.f); return; }

    pack_rows_kernel<<<1, 256, 0, stream>>>(w2, 64, 128, w2s_, w2nz_);
    pack_rows_kernel<<<2, 256, 0, stream>>>(w3, 128, 128, w3s_, w3nz_);
    pack_rows_kernel<<<8, 256, 0, stream>>>(w4, 256, 256, w4s_, w4nz_);
    pack_rows_kernel<<<64, 256, 0, stream>>>(w5, 1024, 512, w5s_, w5nz_);

    dim3 gnb(N, B);
    const int npt = (B * N + 255) / 256;
    // layer 1: knn on x0 (C=3)
    sq_np_kernel<3><<<npt, 256, 0, stream>>>(x0, 3, 0, sqb);
    transpose3_kernel<<<npt, 256, 0, stream>>>(x0, xT);
    knn_fast_kernel<3><<<gnb, 256, 0, stream>>>(xT, sqb, idxb);
    edgeconv1_kernel<3, 64>
        <<<gnb, 64, 0, stream>>>(x0, 3, 0, idxb, w1, a1, s1, b1, p1, xcat, 0);
    // layer 2: knn on x1 (C=64)
    sq_np_kernel<64><<<npt, 256, 0, stream>>>(xcat, 512, 0, sqb);
    transpose_kernel<<<dim3(16, 1, B), 256, 0, stream>>>(xcat, 512, 0, 64, xT);
    knn_fast_kernel<64><<<gnb, 256, 0, stream>>>(xT, sqb, idxb);
    edgeconv_bin_kernel<64, 64>
        <<<gnb, 64, 0, stream>>>(xcat, 512, 0, idxb, w2s_, w2nz_, a2, s2, b2, p2, xcat, 64);
    // layer 3: knn on x2 (C=64)
    sq_np_kernel<64><<<npt, 256, 0, stream>>>(xcat, 512, 64, sqb);
    transpose_kernel<<<dim3(16, 1, B), 256, 0, stream>>>(xcat, 512, 64, 64, xT);
    knn_fast_kernel<64><<<gnb, 256, 0, stream>>>(xT, sqb, idxb);
    edgeconv_bin_kernel<64, 128>
        <<<gnb, 128, 0, stream>>>(xcat, 512, 64, idxb, w3s_, w3nz_, a3, s3, b3, p3, xcat, 128);
    // layer 4: knn on x3 (C=128)
    sq_np_kernel<128><<<npt, 256, 0, stream>>>(xcat, 512, 128, sqb);
    transpose_kernel<<<dim3(16, 2, B), 256, 0, stream>>>(xcat, 512, 128, 128, xT);
    knn_fast_kernel<128><<<gnb, 256, 0, stream>>>(xT, sqb, idxb);
    edgeconv_bin_kernel<128, 256>
        <<<gnb, 256, 0, stream>>>(xcat, 512, 128, idxb, w4s_, w4nz_, a4, s4, b4, p4, xcat, 256);
    // conv1d + pooling
    pack_cols_kernel<<<(B * 16 * N + 255) / 256, 256, 0, stream>>>(xcat, xss, xnzs);
    conv1d_bin_pool_kernel<<<dim3(16, B), 256, 0, stream>>>(xss, xnzs, w5s_, w5nz_, a5, s5, b5,
                                                            p5, pmax, psum);
    pool_reduce_kernel<<<(B * 1024 + 255) / 256, 256, 0, stream>>>(pmax, psum, pooled);
    lin1_kernel<<<B, 512, 0, stream>>>(pooled, wl1, al1, sl1, bl1, pl1, l1o);
    lin2_kernel<<<B, 256, 0, stream>>>(l1o, wl2, al2, sl2, bl2, pl2, l2o);
    lin3_kernel<<<B, 64, 0, stream>>>(l2o, wl3, sl3, bl3, outp);
}

// Round 8
// 1238.855 us; speedup vs baseline: 2.9694x; 2.9694x over previous
//
#include <hip/hip_runtime.h>
#include <math.h>

#define B 16
#define N 1024
#define KNB 20

typedef unsigned int u32;
typedef unsigned long long u64;

__device__ __forceinline__ float sgnf(float v) {
    return (v > 0.f) ? 1.f : ((v < 0.f) ? -1.f : 0.f);
}

__global__ __launch_bounds__(256) void sentinel_kernel(float* __restrict__ out, int n, float v) {
    int i = blockIdx.x * blockDim.x + threadIdx.x;
    if (i < n) out[i] = v;
}

// ---------------- np-exact sq (UNCHANGED arithmetic) ----------------

template <int C>
__global__ __launch_bounds__(256) void sq_np_kernel(const float* __restrict__ x, int Ctot, int c0,
                                                    float* __restrict__ sq) {
    int i = blockIdx.x * blockDim.x + threadIdx.x;
    if (i >= B * N) return;
    int b = i >> 10, n = i & (N - 1);
    const float* xb = x + ((size_t)b * Ctot + c0) * N + n;
    float res;
    if (C < 8) {
        float v0 = xb[0];
        res = __fmul_rn(v0, v0);
        for (int c = 1; c < C; ++c) {
            float v = xb[(size_t)c * N];
            res = __fadd_rn(res, __fmul_rn(v, v));
        }
    } else {
        float r[8];
#pragma unroll
        for (int j = 0; j < 8; ++j) {
            float v = xb[(size_t)j * N];
            r[j] = __fmul_rn(v, v);
        }
        for (int c = 8; c < C; c += 8) {
#pragma unroll
            for (int j = 0; j < 8; ++j) {
                float v = xb[(size_t)(c + j) * N];
                r[j] = __fadd_rn(r[j], __fmul_rn(v, v));
            }
        }
        res = __fadd_rn(__fadd_rn(__fadd_rn(r[0], r[1]), __fadd_rn(r[2], r[3])),
                        __fadd_rn(__fadd_rn(r[4], r[5]), __fadd_rn(r[6], r[7])));
    }
    sq[i] = res;
}

// ---------------- knn: one wave per point, coalesced column-major reads, ----------------
// np-exact distances; top-20 SET via radix-select threshold + ballot compaction.
// Set semantics valid because downstream maxes over k (order-independent); ties
// resolved to lowest indices exactly like stable lax.top_k.
template <int C>
__global__ __launch_bounds__(256) void knn_radix_kernel(const float* __restrict__ x, int Ctot,
                                                        int c0, const float* __restrict__ sq,
                                                        int* __restrict__ idxout) {
    const int b = blockIdx.y;
    const int wave = threadIdx.x >> 6, lane = threadIdx.x & 63;
    const int n = blockIdx.x * 4 + wave;
    __shared__ float xn[4][C];
    const float* xb = x + ((size_t)b * Ctot + c0) * N;
    for (int c = lane; c < C; c += 64) xn[wave][c] = xb[(size_t)c * N + n];
    float acc[16];
#pragma unroll
    for (int j = 0; j < 16; ++j) acc[j] = 0.f;
    for (int c = 0; c < C; ++c) {
        float xv = xn[wave][c];
        const float* row = xb + (size_t)c * N + lane;
#pragma unroll
        for (int j = 0; j < 16; ++j)
            acc[j] = __fadd_rn(acc[j], __fmul_rn(xv, row[j * 64]));
    }
    const float sqn = sq[b * N + n];
    u32 key[16];
#pragma unroll
    for (int j = 0; j < 16; ++j) {
        float d =
            __fsub_rn(__fsub_rn(__fmul_rn(2.f, acc[j]), sqn), sq[b * N + j * 64 + lane]);
        u32 bits = __float_as_uint(d);
        if ((bits << 1) == 0) bits = 0;  // canonicalize -0 -> +0
        key[j] = (bits & 0x80000000u) ? ~bits : (bits | 0x80000000u);
    }
    // T = 20th-largest key: greedy MSB-first max X with count(key >= X) >= 20
    u32 T = 0;
    for (int bpos = 31; bpos >= 0; --bpos) {
        u32 cand = T | (1u << bpos);
        int cnt = 0;
#pragma unroll
        for (int j = 0; j < 16; ++j) cnt += __popcll(__ballot(key[j] >= cand));
        if (cnt >= KNB) T = cand;
    }
    int* out = idxout + ((size_t)b * N + n) * KNB;
    const u64 ltmask = (1ull << lane) - 1ull;
    int base = 0;
#pragma unroll
    for (int j = 0; j < 16; ++j) {
        u64 m = __ballot(key[j] > T);
        if (key[j] > T) out[base + __popcll(m & ltmask)] = j * 64 + lane;
        base += __popcll(m);
    }
    const int R = KNB - base;  // ties needed, filled in ascending index (j asc, lane asc)
    int eqb = 0;
#pragma unroll
    for (int j = 0; j < 16; ++j) {
        u64 m = __ballot(key[j] == T);
        int r = eqb + __popcll(m & ltmask);
        if (key[j] == T && r < R) out[base + r] = j * 64 + lane;
        eqb += __popcll(m);
    }
}

// ---------------- layer-1 edgeconv (np-exact, UNCHANGED) ----------------

template <int C, int COUT>
__global__ __launch_bounds__(COUT) void edgeconv1_kernel(
    const float* __restrict__ xin, int Ctot_in, int c0_in, const int* __restrict__ idx,
    const float* __restrict__ W, const float* __restrict__ aa, const float* __restrict__ ssc,
    const float* __restrict__ bbi, const float* __restrict__ pp, float* __restrict__ xout,
    int c0_out) {
    const int b = blockIdx.y, n = blockIdx.x, tid = threadIdx.x;
    __shared__ float ctr_raw[C];
    __shared__ float ctr_f[C];
    __shared__ __align__(16) float df[C][KNB];
    __shared__ int ids[KNB];
    const float* xb = xin + ((size_t)b * Ctot_in + c0_in) * N;
    if (tid < KNB) ids[tid] = idx[((size_t)b * N + n) * KNB + tid];
    for (int c = tid; c < C; c += COUT) {
        float v = xb[(size_t)c * N + n];
        ctr_raw[c] = v;
        ctr_f[c] = v;
    }
    __syncthreads();
    for (int t = tid; t < C * KNB; t += COUT) {
        int c = t / KNB, k = t - c * KNB;
        df[c][k] = __fsub_rn(xb[(size_t)c * N + ids[k]], ctr_raw[c]);
    }
    __syncthreads();
    const int o = tid;
    const float* wrow = W + (size_t)o * (2 * C);
    const float as = __fmul_rn(aa[o], ssc[o]);
    const float bo = bbi[o], po = pp[o];
    float best = -3.4e38f;
    float wd[C], wc[C];
    for (int c = 0; c < C; ++c) { wd[c] = sgnf(wrow[c]); wc[c] = sgnf(wrow[C + c]); }
    for (int k = 0; k < KNB; ++k) {
        float acc = 0.f;
        for (int c = 0; c < C; ++c) acc = __fadd_rn(acc, __fmul_rn(df[c][k], wd[c]));
        for (int c = 0; c < C; ++c) acc = __fadd_rn(acc, __fmul_rn(ctr_f[c], wc[c]));
        float y = __fadd_rn(__fmul_rn(acc, as), bo);
        y = y > 0.f ? y : __fmul_rn(po, y);
        best = fmaxf(best, y);
    }
    xout[((size_t)b * 512 + (c0_out + o)) * N + n] = best;
}

// ---------------- ternary bitpack helpers (UNCHANGED) ----------------

__global__ __launch_bounds__(256) void pack_rows_kernel(const float* __restrict__ src, int rows,
                                                        int cols, u32* __restrict__ s,
                                                        u32* __restrict__ nz) {
    int i = blockIdx.x * blockDim.x + threadIdx.x;
    int wpr = cols >> 5;
    if (i >= rows * wpr) return;
    int r = i / wpr, w = i - r * wpr;
    const float* p = src + (size_t)r * cols + (size_t)w * 32;
    u32 sb = 0, nb = 0;
    for (int j = 0; j < 32; ++j) {
        float v = p[j];
        if (v < 0.f) sb |= (1u << j);
        if (v != 0.f) nb |= (1u << j);
    }
    s[i] = sb;
    nz[i] = nb;
}

__global__ __launch_bounds__(256) void pack_cols_kernel(const float* __restrict__ x,
                                                        u32* __restrict__ s,
                                                        u32* __restrict__ nz) {
    int i = blockIdx.x * blockDim.x + threadIdx.x;
    if (i >= B * 16 * N) return;
    int n = i & (N - 1);
    int w = (i >> 10) & 15;
    int b = i >> 14;
    const float* p = x + ((size_t)b * 512 + (size_t)w * 32) * N + n;
    u32 sb = 0, nb = 0;
    for (int j = 0; j < 32; ++j) {
        float v = p[(size_t)j * N];
        if (v < 0.f) sb |= (1u << j);
        if (v != 0.f) nb |= (1u << j);
    }
    s[i] = sb;
    nz[i] = nb;
}

// ---------------- binarized edgeconv via xor/popcount (UNCHANGED) ----------------

template <int C, int COUT>
__global__ __launch_bounds__(COUT) void edgeconv_bin_kernel(
    const float* __restrict__ xin, int Ctot_in, int c0_in, const int* __restrict__ idx,
    const u32* __restrict__ wsm, const u32* __restrict__ wnzm, const float* __restrict__ aa,
    const float* __restrict__ ssc, const float* __restrict__ bbi, const float* __restrict__ pp,
    float* __restrict__ xout, int c0_out) {
    constexpr int W = C / 32;
    const int b = blockIdx.y, n = blockIdx.x, tid = threadIdx.x;
    __shared__ float ctr_raw[C];
    __shared__ int ids[KNB];
    __shared__ u32 ctr_s[W], ctr_nz[W];
    __shared__ u32 dfs[KNB][W], dfnz[KNB][W];
    const float* xb = xin + ((size_t)b * Ctot_in + c0_in) * N;
    if (tid < KNB) ids[tid] = idx[((size_t)b * N + n) * KNB + tid];
    if (tid < C) {
        float v = xb[(size_t)tid * N + n];
        ctr_raw[tid] = v;
        u64 bs = __ballot(v < 0.f);
        u64 bnz = __ballot(v != 0.f);
        if ((tid & 63) == 0) {
            int wb = tid >> 5;
            ctr_s[wb] = (u32)bs;       ctr_s[wb + 1] = (u32)(bs >> 32);
            ctr_nz[wb] = (u32)bnz;     ctr_nz[wb + 1] = (u32)(bnz >> 32);
        }
    }
    __syncthreads();
    for (int t = tid; t < KNB * C; t += COUT) {
        int k = t / C, c = t - k * C;
        float v = __fsub_rn(xb[(size_t)c * N + ids[k]], ctr_raw[c]);
        u64 bs = __ballot(v < 0.f);
        u64 bnz = __ballot(v != 0.f);
        if ((c & 63) == 0) {
            int wb = c >> 5;
            dfs[k][wb] = (u32)bs;      dfs[k][wb + 1] = (u32)(bs >> 32);
            dfnz[k][wb] = (u32)bnz;    dfnz[k][wb + 1] = (u32)(bnz >> 32);
        }
    }
    __syncthreads();
    const int o = tid;
    const u32* wsrow = wsm + (size_t)o * 2 * W;
    const u32* wnzrow = wnzm + (size_t)o * 2 * W;
    u32 wds[W], wdnz[W], wcs[W], wcnz[W];
#pragma unroll
    for (int w = 0; w < W; ++w) {
        wds[w] = wsrow[w];      wcs[w] = wsrow[W + w];
        wdnz[w] = wnzrow[w];    wcnz[w] = wnzrow[W + w];
    }
    int cdot = 0;
#pragma unroll
    for (int w = 0; w < W; ++w) {
        u32 nzb = ctr_nz[w] & wcnz[w];
        u32 neg = (ctr_s[w] ^ wcs[w]) & nzb;
        cdot += __popc(nzb) - 2 * __popc(neg);
    }
    const float as = __fmul_rn(aa[o], ssc[o]);
    const float bo = bbi[o], po = pp[o];
    float best = -3.4e38f;
    for (int k = 0; k < KNB; ++k) {
        int dot = cdot;
#pragma unroll
        for (int w = 0; w < W; ++w) {
            u32 nzb = dfnz[k][w] & wdnz[w];
            u32 neg = (dfs[k][w] ^ wds[w]) & nzb;
            dot += __popc(nzb) - 2 * __popc(neg);
        }
        float y = __fadd_rn(__fmul_rn((float)dot, as), bo);
        y = y > 0.f ? y : __fmul_rn(po, y);
        best = fmaxf(best, y);
    }
    xout[((size_t)b * 512 + (c0_out + o)) * N + n] = best;
}

// ---------------- conv1d bitplane popcount + fused pooling (UNCHANGED) ----------------

__global__ __launch_bounds__(256) void conv1d_bin_pool_kernel(
    const u32* __restrict__ xs, const u32* __restrict__ xnz, const u32* __restrict__ w5s,
    const u32* __restrict__ w5nz, const float* __restrict__ aa, const float* __restrict__ ssc,
    const float* __restrict__ bbi, const float* __restrict__ pp, float* __restrict__ pmax,
    float* __restrict__ psum) {
    const int b = blockIdx.y;
    const int otile = blockIdx.x & 3;
    const int nq = blockIdx.x >> 2;
    const int tid = threadIdx.x;
    const int o = otile * 256 + tid;
    __shared__ u32 shs[128][20];
    __shared__ u32 shnz[128][20];
    u32 ws[16], wnz[16];
#pragma unroll
    for (int w = 0; w < 16; ++w) {
        ws[w] = w5s[(size_t)o * 16 + w];
        wnz[w] = w5nz[(size_t)o * 16 + w];
    }
    const float as = __fmul_rn(aa[o], ssc[o]);
    const float bo = bbi[o], po = pp[o];
    float m = -3.4e38f, sum = 0.f;
    for (int half = 0; half < 2; ++half) {
        const int nbase = nq * 256 + half * 128;
        __syncthreads();
        for (int t = tid; t < 16 * 128; t += 256) {
            int w = t >> 7, nl = t & 127;
            shs[nl][w] = xs[((size_t)b * 16 + w) * N + nbase + nl];
            shnz[nl][w] = xnz[((size_t)b * 16 + w) * N + nbase + nl];
        }
        __syncthreads();
        for (int nl = 0; nl < 128; ++nl) {
            int dot = 0;
#pragma unroll
            for (int w = 0; w < 16; ++w) {
                u32 nzb = shnz[nl][w] & wnz[w];
                u32 neg = (shs[nl][w] ^ ws[w]) & nzb;
                dot += __popc(nzb) - 2 * __popc(neg);
            }
            float y = __fadd_rn(__fmul_rn((float)dot, as), bo);
            y = y > 0.f ? y : __fmul_rn(po, y);
            m = fmaxf(m, y);
            sum = __fadd_rn(sum, y);
        }
    }
    pmax[((size_t)b * 1024 + o) * 4 + nq] = m;
    psum[((size_t)b * 1024 + o) * 4 + nq] = sum;
}

__global__ __launch_bounds__(256) void pool_reduce_kernel(const float* __restrict__ pmax,
                                                          const float* __restrict__ psum,
                                                          float* __restrict__ pooled) {
    int i = blockIdx.x * blockDim.x + threadIdx.x;
    if (i >= B * 1024) return;
    int b = i >> 10, o = i & 1023;
    const float* pm = pmax + (size_t)i * 4;
    const float* ps = psum + (size_t)i * 4;
    float m = -3.4e38f, s = 0.f;
    for (int t = 0; t < 4; ++t) { m = fmaxf(m, pm[t]); s = __fadd_rn(s, ps[t]); }
    pooled[(size_t)b * 2048 + o] = m;
    pooled[(size_t)b * 2048 + 1024 + o] = __fmul_rn(s, (1.f / 1024.f));
}

// ---------------- heads (UNCHANGED) ----------------

__global__ __launch_bounds__(512) void lin1_kernel(const float* __restrict__ xin,
                                                   const float* __restrict__ W,
                                                   const float* __restrict__ aa,
                                                   const float* __restrict__ ssc,
                                                   const float* __restrict__ bbi,
                                                   const float* __restrict__ pp,
                                                   float* __restrict__ out) {
    int b = blockIdx.x, tid = threadIdx.x;
    __shared__ float sx[2048];
    for (int c = tid; c < 2048; c += 512) sx[c] = sgnf(xin[b * 2048 + c]);
    __syncthreads();
    int o = tid;
    const float* wrow = W + (size_t)o * 2048;
    float acc = 0.f;
    for (int c = 0; c < 2048; ++c) acc = fmaf(sx[c], sgnf(wrow[c]), acc);
    float y = __fadd_rn(__fmul_rn(acc, __fmul_rn(aa[o], ssc[o])), bbi[o]);
    out[b * 512 + o] = y > 0.f ? y : __fmul_rn(pp[o], y);
}

__global__ __launch_bounds__(256) void lin2_kernel(const float* __restrict__ xin,
                                                   const float* __restrict__ W,
                                                   const float* __restrict__ aa,
                                                   const float* __restrict__ ssc,
                                                   const float* __restrict__ bbi,
                                                   const float* __restrict__ pp,
                                                   float* __restrict__ out) {
    int b = blockIdx.x, tid = threadIdx.x;
    __shared__ float sx[512];
    for (int c = tid; c < 512; c += 256) sx[c] = sgnf(xin[b * 512 + c]);
    __syncthreads();
    int o = tid;
    const float* wrow = W + (size_t)o * 512;
    float acc = 0.f;
    for (int c = 0; c < 512; ++c) acc = fmaf(sx[c], sgnf(wrow[c]), acc);
    float y = __fadd_rn(__fmul_rn(acc, __fmul_rn(aa[o], ssc[o])), bbi[o]);
    out[b * 256 + o] = y > 0.f ? y : __fmul_rn(pp[o], y);
}

__global__ __launch_bounds__(64) void lin3_kernel(const float* __restrict__ xin,
                                                  const float* __restrict__ W,
                                                  const float* __restrict__ ssc,
                                                  const float* __restrict__ bbi,
                                                  float* __restrict__ out) {
    int b = blockIdx.x, j = threadIdx.x;
    if (j >= 40) return;
    const float* wrow = W + j * 256;
    const float* xb = xin + b * 256;
    double acc = 0.0;
    for (int c = 0; c < 256; ++c) acc = fma((double)xb[c], (double)wrow[c], acc);
    out[b * 40 + j] = __fadd_rn(__fmul_rn((float)acc, ssc[j]), bbi[j]);
}

extern "C" void kernel_launch(void* const* d_in, const int* in_sizes, int n_in, void* d_out,
                              int out_size, void* d_ws, size_t ws_size, hipStream_t stream) {
    float* outp = (float*)d_out;
    auto sentinel = [&](float code) {
        sentinel_kernel<<<(640 + 255) / 256, 256, 0, stream>>>(outp, 640, code * 1.0e6f);
    };
    if (n_in != 39) { sentinel(1.f); return; }
    static const int expect[39] = {
        16 * 3 * 1024,
        64 * 6, 64, 64, 64, 64,
        64 * 128, 64, 64, 64, 64,
        128 * 128, 128, 128, 128, 128,
        256 * 256, 256, 256, 256, 256,
        1024 * 512, 1024, 1024, 1024, 1024,
        512 * 2048, 512, 512, 512, 512,
        256 * 512, 256, 256, 256, 256,
        40 * 256, 40, 40
    };
    for (int i = 0; i < 39; ++i)
        if (in_sizes[i] != expect[i]) { sentinel(2.f); return; }
    if (out_size != 640) { sentinel(3.f); return; }

    const float* x0 = (const float*)d_in[0];
    const float *w1 = (const float*)d_in[1], *a1 = (const float*)d_in[2],
                *s1 = (const float*)d_in[3], *b1 = (const float*)d_in[4],
                *p1 = (const float*)d_in[5];
    const float *a2 = (const float*)d_in[7], *s2 = (const float*)d_in[8],
                *b2 = (const float*)d_in[9], *p2 = (const float*)d_in[10];
    const float *a3 = (const float*)d_in[12], *s3 = (const float*)d_in[13],
                *b3 = (const float*)d_in[14], *p3 = (const float*)d_in[15];
    const float *a4 = (const float*)d_in[17], *s4 = (const float*)d_in[18],
                *b4 = (const float*)d_in[19], *p4 = (const float*)d_in[20];
    const float *a5 = (const float*)d_in[22], *s5 = (const float*)d_in[23],
                *b5 = (const float*)d_in[24], *p5 = (const float*)d_in[25];
    const float *w2 = (const float*)d_in[6], *w3 = (const float*)d_in[11],
                *w4 = (const float*)d_in[16], *w5 = (const float*)d_in[21];
    const float *wl1 = (const float*)d_in[26], *al1 = (const float*)d_in[27],
                *sl1 = (const float*)d_in[28], *bl1 = (const float*)d_in[29],
                *pl1 = (const float*)d_in[30];
    const float *wl2 = (const float*)d_in[31], *al2 = (const float*)d_in[32],
                *sl2 = (const float*)d_in[33], *bl2 = (const float*)d_in[34],
                *pl2 = (const float*)d_in[35];
    const float *wl3 = (const float*)d_in[36], *sl3 = (const float*)d_in[37],
                *bl3 = (const float*)d_in[38];

    char* ws = (char*)d_ws;
    size_t off = 0;
    auto alloc = [&](size_t bytes) -> void* {
        void* p = ws + off;
        off += (bytes + 255) & ~(size_t)255;
        return p;
    };
    float* xcat = (float*)alloc((size_t)B * 512 * N * 4);
    int* idxb = (int*)alloc((size_t)B * N * KNB * 4);
    float* sqb = (float*)alloc((size_t)B * N * 4);
    u32* w2s_ = (u32*)alloc(64 * 4 * 4);     u32* w2nz_ = (u32*)alloc(64 * 4 * 4);
    u32* w3s_ = (u32*)alloc(128 * 4 * 4);    u32* w3nz_ = (u32*)alloc(128 * 4 * 4);
    u32* w4s_ = (u32*)alloc(256 * 8 * 4);    u32* w4nz_ = (u32*)alloc(256 * 8 * 4);
    u32* w5s_ = (u32*)alloc(1024 * 16 * 4);  u32* w5nz_ = (u32*)alloc(1024 * 16 * 4);
    u32* xss = (u32*)alloc((size_t)B * 16 * N * 4);
    u32* xnzs = (u32*)alloc((size_t)B * 16 * N * 4);
    float* pmax = (float*)alloc((size_t)B * 1024 * 4 * 4);
    float* psum = (float*)alloc((size_t)B * 1024 * 4 * 4);
    float* pooled = (float*)alloc((size_t)B * 2048 * 4);
    float* l1o = (float*)alloc((size_t)B * 512 * 4);
    float* l2o = (float*)alloc((size_t)B * 256 * 4);
    if (off > ws_size) { sentinel(4.f); return; }

    pack_rows_kernel<<<1, 256, 0, stream>>>(w2, 64, 128, w2s_, w2nz_);
    pack_rows_kernel<<<2, 256, 0, stream>>>(w3, 128, 128, w3s_, w3nz_);
    pack_rows_kernel<<<8, 256, 0, stream>>>(w4, 256, 256, w4s_, w4nz_);
    pack_rows_kernel<<<64, 256, 0, stream>>>(w5, 1024, 512, w5s_, w5nz_);

    dim3 gnb(N, B);
    dim3 gknn(N / 4, B);
    const int npt = (B * N + 255) / 256;
    // layer 1: knn on x0 (C=3)
    sq_np_kernel<3><<<npt, 256, 0, stream>>>(x0, 3, 0, sqb);
    knn_radix_kernel<3><<<gknn, 256, 0, stream>>>(x0, 3, 0, sqb, idxb);
    edgeconv1_kernel<3, 64>
        <<<gnb, 64, 0, stream>>>(x0, 3, 0, idxb, w1, a1, s1, b1, p1, xcat, 0);
    // layer 2: knn on x1 (C=64)
    sq_np_kernel<64><<<npt, 256, 0, stream>>>(xcat, 512, 0, sqb);
    knn_radix_kernel<64><<<gknn, 256, 0, stream>>>(xcat, 512, 0, sqb, idxb);
    edgeconv_bin_kernel<64, 64>
        <<<gnb, 64, 0, stream>>>(xcat, 512, 0, idxb, w2s_, w2nz_, a2, s2, b2, p2, xcat, 64);
    // layer 3: knn on x2 (C=64)
    sq_np_kernel<64><<<npt, 256, 0, stream>>>(xcat, 512, 64, sqb);
    knn_radix_kernel<64><<<gknn, 256, 0, stream>>>(xcat, 512, 64, sqb, idxb);
    edgeconv_bin_kernel<64, 128>
        <<<gnb, 128, 0, stream>>>(xcat, 512, 64, idxb, w3s_, w3nz_, a3, s3, b3, p3, xcat, 128);
    // layer 4: knn on x3 (C=128)
    sq_np_kernel<128><<<npt, 256, 0, stream>>>(xcat, 512, 128, sqb);
    knn_radix_kernel<128><<<gknn, 256, 0, stream>>>(xcat, 512, 128, sqb, idxb);
    edgeconv_bin_kernel<128, 256>
        <<<gnb, 256, 0, stream>>>(xcat, 512, 128, idxb, w4s_, w4nz_, a4, s4, b4, p4, xcat, 256);
    // conv1d + pooling
    pack_cols_kernel<<<(B * 16 * N + 255) / 256, 256, 0, stream>>>(xcat, xss, xnzs);
    conv1d_bin_pool_kernel<<<dim3(16, B), 256, 0, stream>>>(xss, xnzs, w5s_, w5nz_, a5, s5, b5,
                                                            p5, pmax, psum);
    pool_reduce_kernel<<<(B * 1024 + 255) / 256, 256, 0, stream>>>(pmax, psum, pooled);
    lin1_kernel<<<B, 512, 0, stream>>>(pooled, wl1, al1, sl1, bl1, pl1, l1o);
    lin2_kernel<<<B, 256, 0, stream>>>(l1o, wl2, al2, sl2, bl2, pl2, l2o);
    lin3_kernel<<<B, 64, 0, stream>>>(l2o, wl3, sl3, bl3, outp);
}

// Round 9
// 1031.144 us; speedup vs baseline: 3.5675x; 1.2014x over previous
//
#include <hip/hip_runtime.h>
#include <math.h>

#define B 16
#define N 1024
#define KNB 20

typedef unsigned int u32;
typedef unsigned long long u64;

__device__ __forceinline__ float sgnf(float v) {
    return (v > 0.f) ? 1.f : ((v < 0.f) ? -1.f : 0.f);
}

__global__ __launch_bounds__(256) void sentinel_kernel(float* __restrict__ out, int n, float v) {
    int i = blockIdx.x * blockDim.x + threadIdx.x;
    if (i < n) out[i] = v;
}

// ---------------- np-exact sq (UNCHANGED arithmetic) ----------------

template <int C>
__global__ __launch_bounds__(256) void sq_np_kernel(const float* __restrict__ x, int Ctot, int c0,
                                                    float* __restrict__ sq) {
    int i = blockIdx.x * blockDim.x + threadIdx.x;
    if (i >= B * N) return;
    int b = i >> 10, n = i & (N - 1);
    const float* xb = x + ((size_t)b * Ctot + c0) * N + n;
    float res;
    if (C < 8) {
        float v0 = xb[0];
        res = __fmul_rn(v0, v0);
        for (int c = 1; c < C; ++c) {
            float v = xb[(size_t)c * N];
            res = __fadd_rn(res, __fmul_rn(v, v));
        }
    } else {
        float r[8];
#pragma unroll
        for (int j = 0; j < 8; ++j) {
            float v = xb[(size_t)j * N];
            r[j] = __fmul_rn(v, v);
        }
        for (int c = 8; c < C; c += 8) {
#pragma unroll
            for (int j = 0; j < 8; ++j) {
                float v = xb[(size_t)(c + j) * N];
                r[j] = __fadd_rn(r[j], __fmul_rn(v, v));
            }
        }
        res = __fadd_rn(__fadd_rn(__fadd_rn(r[0], r[1]), __fadd_rn(r[2], r[3])),
                        __fadd_rn(__fadd_rn(r[4], r[5]), __fadd_rn(r[6], r[7])));
    }
    sq[i] = res;
}

// ---------------- knn: 4 points per wave, 16 per block; np-exact distances; ----------------
// top-20 SET via radix threshold + ballot compaction (ties -> lowest index, exact).
template <int C>
__global__ __launch_bounds__(256) void knn_radix4_kernel(const float* __restrict__ x, int Ctot,
                                                         int c0, const float* __restrict__ sq,
                                                         int* __restrict__ idxout) {
    const int b = blockIdx.y;
    const int tid = threadIdx.x, wave = tid >> 6, lane = tid & 63;
    const int nbase = blockIdx.x * 16;
    __shared__ float xn[16][C];
    const float* xb = x + ((size_t)b * Ctot + c0) * N;
    for (int t = tid; t < 16 * C; t += 256) {
        int pt = t & 15, c = t >> 4;
        xn[pt][c] = xb[(size_t)c * N + nbase + pt];
    }
    __syncthreads();
    float acc[4][16];
#pragma unroll
    for (int p = 0; p < 4; ++p)
#pragma unroll
        for (int j = 0; j < 16; ++j) acc[p][j] = 0.f;
    const float* xw0 = &xn[wave * 4 + 0][0];
    const float* xw1 = &xn[wave * 4 + 1][0];
    const float* xw2 = &xn[wave * 4 + 2][0];
    const float* xw3 = &xn[wave * 4 + 3][0];
    for (int c = 0; c < C; ++c) {
        const float* row = xb + (size_t)c * N + lane;
        float xv0 = xw0[c], xv1 = xw1[c], xv2 = xw2[c], xv3 = xw3[c];
#pragma unroll
        for (int j = 0; j < 16; ++j) {
            float rv = row[j * 64];
            acc[0][j] = __fadd_rn(acc[0][j], __fmul_rn(xv0, rv));
            acc[1][j] = __fadd_rn(acc[1][j], __fmul_rn(xv1, rv));
            acc[2][j] = __fadd_rn(acc[2][j], __fmul_rn(xv2, rv));
            acc[3][j] = __fadd_rn(acc[3][j], __fmul_rn(xv3, rv));
        }
    }
    float sqm[16];
#pragma unroll
    for (int j = 0; j < 16; ++j) sqm[j] = sq[b * N + j * 64 + lane];
    const u64 ltmask = (1ull << lane) - 1ull;
#pragma unroll
    for (int p = 0; p < 4; ++p) {
        const int n = nbase + wave * 4 + p;
        const float sqn = sq[b * N + n];
        u32 key[16];
#pragma unroll
        for (int j = 0; j < 16; ++j) {
            float d = __fsub_rn(__fsub_rn(__fmul_rn(2.f, acc[p][j]), sqn), sqm[j]);
            u32 bits = __float_as_uint(d);
            if ((bits << 1) == 0) bits = 0;  // canonicalize -0 -> +0
            key[j] = (bits & 0x80000000u) ? ~bits : (bits | 0x80000000u);
        }
        u32 T = 0;
        for (int bpos = 31; bpos >= 0; --bpos) {
            u32 cand = T | (1u << bpos);
            int cnt = 0;
#pragma unroll
            for (int j = 0; j < 16; ++j) cnt += __popcll(__ballot(key[j] >= cand));
            if (cnt >= KNB) T = cand;
        }
        int* out = idxout + ((size_t)b * N + n) * KNB;
        int base = 0;
#pragma unroll
        for (int j = 0; j < 16; ++j) {
            u64 m = __ballot(key[j] > T);
            if (key[j] > T) out[base + __popcll(m & ltmask)] = j * 64 + lane;
            base += __popcll(m);
        }
        const int R = KNB - base;  // ties, filled ascending index (j asc, lane asc)
        int eqb = 0;
#pragma unroll
        for (int j = 0; j < 16; ++j) {
            u64 m = __ballot(key[j] == T);
            int r = eqb + __popcll(m & ltmask);
            if (key[j] == T && r < R) out[base + r] = j * 64 + lane;
            eqb += __popcll(m);
        }
    }
}

// ---------------- layer-1 edgeconv (np-exact, UNCHANGED) ----------------

template <int C, int COUT>
__global__ __launch_bounds__(COUT) void edgeconv1_kernel(
    const float* __restrict__ xin, int Ctot_in, int c0_in, const int* __restrict__ idx,
    const float* __restrict__ W, const float* __restrict__ aa, const float* __restrict__ ssc,
    const float* __restrict__ bbi, const float* __restrict__ pp, float* __restrict__ xout,
    int c0_out) {
    const int b = blockIdx.y, n = blockIdx.x, tid = threadIdx.x;
    __shared__ float ctr_raw[C];
    __shared__ float ctr_f[C];
    __shared__ __align__(16) float df[C][KNB];
    __shared__ int ids[KNB];
    const float* xb = xin + ((size_t)b * Ctot_in + c0_in) * N;
    if (tid < KNB) ids[tid] = idx[((size_t)b * N + n) * KNB + tid];
    for (int c = tid; c < C; c += COUT) {
        float v = xb[(size_t)c * N + n];
        ctr_raw[c] = v;
        ctr_f[c] = v;
    }
    __syncthreads();
    for (int t = tid; t < C * KNB; t += COUT) {
        int c = t / KNB, k = t - c * KNB;
        df[c][k] = __fsub_rn(xb[(size_t)c * N + ids[k]], ctr_raw[c]);
    }
    __syncthreads();
    const int o = tid;
    const float* wrow = W + (size_t)o * (2 * C);
    const float as = __fmul_rn(aa[o], ssc[o]);
    const float bo = bbi[o], po = pp[o];
    float best = -3.4e38f;
    float wd[C], wc[C];
    for (int c = 0; c < C; ++c) { wd[c] = sgnf(wrow[c]); wc[c] = sgnf(wrow[C + c]); }
    for (int k = 0; k < KNB; ++k) {
        float acc = 0.f;
        for (int c = 0; c < C; ++c) acc = __fadd_rn(acc, __fmul_rn(df[c][k], wd[c]));
        for (int c = 0; c < C; ++c) acc = __fadd_rn(acc, __fmul_rn(ctr_f[c], wc[c]));
        float y = __fadd_rn(__fmul_rn(acc, as), bo);
        y = y > 0.f ? y : __fmul_rn(po, y);
        best = fmaxf(best, y);
    }
    xout[((size_t)b * 512 + (c0_out + o)) * N + n] = best;
}

// ---------------- ternary bitpack helpers (UNCHANGED) ----------------

__global__ __launch_bounds__(256) void pack_rows_kernel(const float* __restrict__ src, int rows,
                                                        int cols, u32* __restrict__ s,
                                                        u32* __restrict__ nz) {
    int i = blockIdx.x * blockDim.x + threadIdx.x;
    int wpr = cols >> 5;
    if (i >= rows * wpr) return;
    int r = i / wpr, w = i - r * wpr;
    const float* p = src + (size_t)r * cols + (size_t)w * 32;
    u32 sb = 0, nb = 0;
    for (int j = 0; j < 32; ++j) {
        float v = p[j];
        if (v < 0.f) sb |= (1u << j);
        if (v != 0.f) nb |= (1u << j);
    }
    s[i] = sb;
    nz[i] = nb;
}

__global__ __launch_bounds__(256) void pack_cols_kernel(const float* __restrict__ x,
                                                        u32* __restrict__ s,
                                                        u32* __restrict__ nz) {
    int i = blockIdx.x * blockDim.x + threadIdx.x;
    if (i >= B * 16 * N) return;
    int n = i & (N - 1);
    int w = (i >> 10) & 15;
    int b = i >> 14;
    const float* p = x + ((size_t)b * 512 + (size_t)w * 32) * N + n;
    u32 sb = 0, nb = 0;
    for (int j = 0; j < 32; ++j) {
        float v = p[(size_t)j * N];
        if (v < 0.f) sb |= (1u << j);
        if (v != 0.f) nb |= (1u << j);
    }
    s[i] = sb;
    nz[i] = nb;
}

// ---------------- binarized edgeconv via xor/popcount (UNCHANGED) ----------------

template <int C, int COUT>
__global__ __launch_bounds__(COUT) void edgeconv_bin_kernel(
    const float* __restrict__ xin, int Ctot_in, int c0_in, const int* __restrict__ idx,
    const u32* __restrict__ wsm, const u32* __restrict__ wnzm, const float* __restrict__ aa,
    const float* __restrict__ ssc, const float* __restrict__ bbi, const float* __restrict__ pp,
    float* __restrict__ xout, int c0_out) {
    constexpr int W = C / 32;
    const int b = blockIdx.y, n = blockIdx.x, tid = threadIdx.x;
    __shared__ float ctr_raw[C];
    __shared__ int ids[KNB];
    __shared__ u32 ctr_s[W], ctr_nz[W];
    __shared__ u32 dfs[KNB][W], dfnz[KNB][W];
    const float* xb = xin + ((size_t)b * Ctot_in + c0_in) * N;
    if (tid < KNB) ids[tid] = idx[((size_t)b * N + n) * KNB + tid];
    if (tid < C) {
        float v = xb[(size_t)tid * N + n];
        ctr_raw[tid] = v;
        u64 bs = __ballot(v < 0.f);
        u64 bnz = __ballot(v != 0.f);
        if ((tid & 63) == 0) {
            int wb = tid >> 5;
            ctr_s[wb] = (u32)bs;       ctr_s[wb + 1] = (u32)(bs >> 32);
            ctr_nz[wb] = (u32)bnz;     ctr_nz[wb + 1] = (u32)(bnz >> 32);
        }
    }
    __syncthreads();
    for (int t = tid; t < KNB * C; t += COUT) {
        int k = t / C, c = t - k * C;
        float v = __fsub_rn(xb[(size_t)c * N + ids[k]], ctr_raw[c]);
        u64 bs = __ballot(v < 0.f);
        u64 bnz = __ballot(v != 0.f);
        if ((c & 63) == 0) {
            int wb = c >> 5;
            dfs[k][wb] = (u32)bs;      dfs[k][wb + 1] = (u32)(bs >> 32);
            dfnz[k][wb] = (u32)bnz;    dfnz[k][wb + 1] = (u32)(bnz >> 32);
        }
    }
    __syncthreads();
    const int o = tid;
    const u32* wsrow = wsm + (size_t)o * 2 * W;
    const u32* wnzrow = wnzm + (size_t)o * 2 * W;
    u32 wds[W], wdnz[W], wcs[W], wcnz[W];
#pragma unroll
    for (int w = 0; w < W; ++w) {
        wds[w] = wsrow[w];      wcs[w] = wsrow[W + w];
        wdnz[w] = wnzrow[w];    wcnz[w] = wnzrow[W + w];
    }
    int cdot = 0;
#pragma unroll
    for (int w = 0; w < W; ++w) {
        u32 nzb = ctr_nz[w] & wcnz[w];
        u32 neg = (ctr_s[w] ^ wcs[w]) & nzb;
        cdot += __popc(nzb) - 2 * __popc(neg);
    }
    const float as = __fmul_rn(aa[o], ssc[o]);
    const float bo = bbi[o], po = pp[o];
    float best = -3.4e38f;
    for (int k = 0; k < KNB; ++k) {
        int dot = cdot;
#pragma unroll
        for (int w = 0; w < W; ++w) {
            u32 nzb = dfnz[k][w] & wdnz[w];
            u32 neg = (dfs[k][w] ^ wds[w]) & nzb;
            dot += __popc(nzb) - 2 * __popc(neg);
        }
        float y = __fadd_rn(__fmul_rn((float)dot, as), bo);
        y = y > 0.f ? y : __fmul_rn(po, y);
        best = fmaxf(best, y);
    }
    xout[((size_t)b * 512 + (c0_out + o)) * N + n] = best;
}

// ---------------- conv1d bitplane popcount + fused pooling (UNCHANGED) ----------------

__global__ __launch_bounds__(256) void conv1d_bin_pool_kernel(
    const u32* __restrict__ xs, const u32* __restrict__ xnz, const u32* __restrict__ w5s,
    const u32* __restrict__ w5nz, const float* __restrict__ aa, const float* __restrict__ ssc,
    const float* __restrict__ bbi, const float* __restrict__ pp, float* __restrict__ pmax,
    float* __restrict__ psum) {
    const int b = blockIdx.y;
    const int otile = blockIdx.x & 3;
    const int nq = blockIdx.x >> 2;
    const int tid = threadIdx.x;
    const int o = otile * 256 + tid;
    __shared__ u32 shs[128][20];
    __shared__ u32 shnz[128][20];
    u32 ws[16], wnz[16];
#pragma unroll
    for (int w = 0; w < 16; ++w) {
        ws[w] = w5s[(size_t)o * 16 + w];
        wnz[w] = w5nz[(size_t)o * 16 + w];
    }
    const float as = __fmul_rn(aa[o], ssc[o]);
    const float bo = bbi[o], po = pp[o];
    float m = -3.4e38f, sum = 0.f;
    for (int half = 0; half < 2; ++half) {
        const int nbase = nq * 256 + half * 128;
        __syncthreads();
        for (int t = tid; t < 16 * 128; t += 256) {
            int w = t >> 7, nl = t & 127;
            shs[nl][w] = xs[((size_t)b * 16 + w) * N + nbase + nl];
            shnz[nl][w] = xnz[((size_t)b * 16 + w) * N + nbase + nl];
        }
        __syncthreads();
        for (int nl = 0; nl < 128; ++nl) {
            int dot = 0;
#pragma unroll
            for (int w = 0; w < 16; ++w) {
                u32 nzb = shnz[nl][w] & wnz[w];
                u32 neg = (shs[nl][w] ^ ws[w]) & nzb;
                dot += __popc(nzb) - 2 * __popc(neg);
            }
            float y = __fadd_rn(__fmul_rn((float)dot, as), bo);
            y = y > 0.f ? y : __fmul_rn(po, y);
            m = fmaxf(m, y);
            sum = __fadd_rn(sum, y);
        }
    }
    pmax[((size_t)b * 1024 + o) * 4 + nq] = m;
    psum[((size_t)b * 1024 + o) * 4 + nq] = sum;
}

__global__ __launch_bounds__(256) void pool_reduce_kernel(const float* __restrict__ pmax,
                                                          const float* __restrict__ psum,
                                                          float* __restrict__ pooled) {
    int i = blockIdx.x * blockDim.x + threadIdx.x;
    if (i >= B * 1024) return;
    int b = i >> 10, o = i & 1023;
    const float* pm = pmax + (size_t)i * 4;
    const float* ps = psum + (size_t)i * 4;
    float m = -3.4e38f, s = 0.f;
    for (int t = 0; t < 4; ++t) { m = fmaxf(m, pm[t]); s = __fadd_rn(s, ps[t]); }
    pooled[(size_t)b * 2048 + o] = m;
    pooled[(size_t)b * 2048 + 1024 + o] = __fmul_rn(s, (1.f / 1024.f));
}

// ---------------- heads (UNCHANGED) ----------------

__global__ __launch_bounds__(512) void lin1_kernel(const float* __restrict__ xin,
                                                   const float* __restrict__ W,
                                                   const float* __restrict__ aa,
                                                   const float* __restrict__ ssc,
                                                   const float* __restrict__ bbi,
                                                   const float* __restrict__ pp,
                                                   float* __restrict__ out) {
    int b = blockIdx.x, tid = threadIdx.x;
    __shared__ float sx[2048];
    for (int c = tid; c < 2048; c += 512) sx[c] = sgnf(xin[b * 2048 + c]);
    __syncthreads();
    int o = tid;
    const float* wrow = W + (size_t)o * 2048;
    float acc = 0.f;
    for (int c = 0; c < 2048; ++c) acc = fmaf(sx[c], sgnf(wrow[c]), acc);
    float y = __fadd_rn(__fmul_rn(acc, __fmul_rn(aa[o], ssc[o])), bbi[o]);
    out[b * 512 + o] = y > 0.f ? y : __fmul_rn(pp[o], y);
}

__global__ __launch_bounds__(256) void lin2_kernel(const float* __restrict__ xin,
                                                   const float* __restrict__ W,
                                                   const float* __restrict__ aa,
                                                   const float* __restrict__ ssc,
                                                   const float* __restrict__ bbi,
                                                   const float* __restrict__ pp,
                                                   float* __restrict__ out) {
    int b = blockIdx.x, tid = threadIdx.x;
    __shared__ float sx[512];
    for (int c = tid; c < 512; c += 256) sx[c] = sgnf(xin[b * 512 + c]);
    __syncthreads();
    int o = tid;
    const float* wrow = W + (size_t)o * 512;
    float acc = 0.f;
    for (int c = 0; c < 512; ++c) acc = fmaf(sx[c], sgnf(wrow[c]), acc);
    float y = __fadd_rn(__fmul_rn(acc, __fmul_rn(aa[o], ssc[o])), bbi[o]);
    out[b * 256 + o] = y > 0.f ? y : __fmul_rn(pp[o], y);
}

__global__ __launch_bounds__(64) void lin3_kernel(const float* __restrict__ xin,
                                                  const float* __restrict__ W,
                                                  const float* __restrict__ ssc,
                                                  const float* __restrict__ bbi,
                                                  float* __restrict__ out) {
    int b = blockIdx.x, j = threadIdx.x;
    if (j >= 40) return;
    const float* wrow = W + j * 256;
    const float* xb = xin + b * 256;
    double acc = 0.0;
    for (int c = 0; c < 256; ++c) acc = fma((double)xb[c], (double)wrow[c], acc);
    out[b * 40 + j] = __fadd_rn(__fmul_rn((float)acc, ssc[j]), bbi[j]);
}

extern "C" void kernel_launch(void* const* d_in, const int* in_sizes, int n_in, void* d_out,
                              int out_size, void* d_ws, size_t ws_size, hipStream_t stream) {
    float* outp = (float*)d_out;
    auto sentinel = [&](float code) {
        sentinel_kernel<<<(640 + 255) / 256, 256, 0, stream>>>(outp, 640, code * 1.0e6f);
    };
    if (n_in != 39) { sentinel(1.f); return; }
    static const int expect[39] = {
        16 * 3 * 1024,
        64 * 6, 64, 64, 64, 64,
        64 * 128, 64, 64, 64, 64,
        128 * 128, 128, 128, 128, 128,
        256 * 256, 256, 256, 256, 256,
        1024 * 512, 1024, 1024, 1024, 1024,
        512 * 2048, 512, 512, 512, 512,
        256 * 512, 256, 256, 256, 256,
        40 * 256, 40, 40
    };
    for (int i = 0; i < 39; ++i)
        if (in_sizes[i] != expect[i]) { sentinel(2.f); return; }
    if (out_size != 640) { sentinel(3.f); return; }

    const float* x0 = (const float*)d_in[0];
    const float *w1 = (const float*)d_in[1], *a1 = (const float*)d_in[2],
                *s1 = (const float*)d_in[3], *b1 = (const float*)d_in[4],
                *p1 = (const float*)d_in[5];
    const float *a2 = (const float*)d_in[7], *s2 = (const float*)d_in[8],
                *b2 = (const float*)d_in[9], *p2 = (const float*)d_in[10];
    const float *a3 = (const float*)d_in[12], *s3 = (const float*)d_in[13],
                *b3 = (const float*)d_in[14], *p3 = (const float*)d_in[15];
    const float *a4 = (const float*)d_in[17], *s4 = (const float*)d_in[18],
                *b4 = (const float*)d_in[19], *p4 = (const float*)d_in[20];
    const float *a5 = (const float*)d_in[22], *s5 = (const float*)d_in[23],
                *b5 = (const float*)d_in[24], *p5 = (const float*)d_in[25];
    const float *w2 = (const float*)d_in[6], *w3 = (const float*)d_in[11],
                *w4 = (const float*)d_in[16], *w5 = (const float*)d_in[21];
    const float *wl1 = (const float*)d_in[26], *al1 = (const float*)d_in[27],
                *sl1 = (const float*)d_in[28], *bl1 = (const float*)d_in[29],
                *pl1 = (const float*)d_in[30];
    const float *wl2 = (const float*)d_in[31], *al2 = (const float*)d_in[32],
                *sl2 = (const float*)d_in[33], *bl2 = (const float*)d_in[34],
                *pl2 = (const float*)d_in[35];
    const float *wl3 = (const float*)d_in[36], *sl3 = (const float*)d_in[37],
                *bl3 = (const float*)d_in[38];

    char* ws = (char*)d_ws;
    size_t off = 0;
    auto alloc = [&](size_t bytes) -> void* {
        void* p = ws + off;
        off += (bytes + 255) & ~(size_t)255;
        return p;
    };
    float* xcat = (float*)alloc((size_t)B * 512 * N * 4);
    int* idxb = (int*)alloc((size_t)B * N * KNB * 4);
    float* sqb = (float*)alloc((size_t)B * N * 4);
    u32* w2s_ = (u32*)alloc(64 * 4 * 4);     u32* w2nz_ = (u32*)alloc(64 * 4 * 4);
    u32* w3s_ = (u32*)alloc(128 * 4 * 4);    u32* w3nz_ = (u32*)alloc(128 * 4 * 4);
    u32* w4s_ = (u32*)alloc(256 * 8 * 4);    u32* w4nz_ = (u32*)alloc(256 * 8 * 4);
    u32* w5s_ = (u32*)alloc(1024 * 16 * 4);  u32* w5nz_ = (u32*)alloc(1024 * 16 * 4);
    u32* xss = (u32*)alloc((size_t)B * 16 * N * 4);
    u32* xnzs = (u32*)alloc((size_t)B * 16 * N * 4);
    float* pmax = (float*)alloc((size_t)B * 1024 * 4 * 4);
    float* psum = (float*)alloc((size_t)B * 1024 * 4 * 4);
    float* pooled = (float*)alloc((size_t)B * 2048 * 4);
    float* l1o = (float*)alloc((size_t)B * 512 * 4);
    float* l2o = (float*)alloc((size_t)B * 256 * 4);
    if (off > ws_size) { sentinel(4.f); return; }

    pack_rows_kernel<<<1, 256, 0, stream>>>(w2, 64, 128, w2s_, w2nz_);
    pack_rows_kernel<<<2, 256, 0, stream>>>(w3, 128, 128, w3s_, w3nz_);
    pack_rows_kernel<<<8, 256, 0, stream>>>(w4, 256, 256, w4s_, w4nz_);
    pack_rows_kernel<<<64, 256, 0, stream>>>(w5, 1024, 512, w5s_, w5nz_);

    dim3 gnb(N, B);
    dim3 gknn(N / 16, B);
    const int npt = (B * N + 255) / 256;
    // layer 1: knn on x0 (C=3)
    sq_np_kernel<3><<<npt, 256, 0, stream>>>(x0, 3, 0, sqb);
    knn_radix4_kernel<3><<<gknn, 256, 0, stream>>>(x0, 3, 0, sqb, idxb);
    edgeconv1_kernel<3, 64>
        <<<gnb, 64, 0, stream>>>(x0, 3, 0, idxb, w1, a1, s1, b1, p1, xcat, 0);
    // layer 2: knn on x1 (C=64)
    sq_np_kernel<64><<<npt, 256, 0, stream>>>(xcat, 512, 0, sqb);
    knn_radix4_kernel<64><<<gknn, 256, 0, stream>>>(xcat, 512, 0, sqb, idxb);
    edgeconv_bin_kernel<64, 64>
        <<<gnb, 64, 0, stream>>>(xcat, 512, 0, idxb, w2s_, w2nz_, a2, s2, b2, p2, xcat, 64);
    // layer 3: knn on x2 (C=64)
    sq_np_kernel<64><<<npt, 256, 0, stream>>>(xcat, 512, 64, sqb);
    knn_radix4_kernel<64><<<gknn, 256, 0, stream>>>(xcat, 512, 64, sqb, idxb);
    edgeconv_bin_kernel<64, 128>
        <<<gnb, 128, 0, stream>>>(xcat, 512, 64, idxb, w3s_, w3nz_, a3, s3, b3, p3, xcat, 128);
    // layer 4: knn on x3 (C=128)
    sq_np_kernel<128><<<npt, 256, 0, stream>>>(xcat, 512, 128, sqb);
    knn_radix4_kernel<128><<<gknn, 256, 0, stream>>>(xcat, 512, 128, sqb, idxb);
    edgeconv_bin_kernel<128, 256>
        <<<gnb, 256, 0, stream>>>(xcat, 512, 128, idxb, w4s_, w4nz_, a4, s4, b4, p4, xcat, 256);
    // conv1d + pooling
    pack_cols_kernel<<<(B * 16 * N + 255) / 256, 256, 0, stream>>>(xcat, xss, xnzs);
    conv1d_bin_pool_kernel<<<dim3(16, B), 256, 0, stream>>>(xss, xnzs, w5s_, w5nz_, a5, s5, b5,
                                                            p5, pmax, psum);
    pool_reduce_kernel<<<(B * 1024 + 255) / 256, 256, 0, stream>>>(pmax, psum, pooled);
    lin1_kernel<<<B, 512, 0, stream>>>(pooled, wl1, al1, sl1, bl1, pl1, l1o);
    lin2_kernel<<<B, 256, 0, stream>>>(l1o, wl2, al2, sl2, bl2, pl2, l2o);
    lin3_kernel<<<B, 64, 0, stream>>>(l2o, wl3, sl3, bl3, outp);
}

// Round 10
// 779.254 us; speedup vs baseline: 4.7207x; 1.3232x over previous
//
#include <hip/hip_runtime.h>
#include <math.h>

#define B 16
#define N 1024
#define KNB 20

typedef unsigned int u32;
typedef unsigned long long u64;

__device__ __forceinline__ float sgnf(float v) {
    return (v > 0.f) ? 1.f : ((v < 0.f) ? -1.f : 0.f);
}

__global__ __launch_bounds__(256) void sentinel_kernel(float* __restrict__ out, int n, float v) {
    int i = blockIdx.x * blockDim.x + threadIdx.x;
    if (i < n) out[i] = v;
}

// ---------------- np-exact sq (UNCHANGED arithmetic) ----------------

template <int C>
__global__ __launch_bounds__(256) void sq_np_kernel(const float* __restrict__ x, int Ctot, int c0,
                                                    float* __restrict__ sq) {
    int i = blockIdx.x * blockDim.x + threadIdx.x;
    if (i >= B * N) return;
    int b = i >> 10, n = i & (N - 1);
    const float* xb = x + ((size_t)b * Ctot + c0) * N + n;
    float res;
    if (C < 8) {
        float v0 = xb[0];
        res = __fmul_rn(v0, v0);
        for (int c = 1; c < C; ++c) {
            float v = xb[(size_t)c * N];
            res = __fadd_rn(res, __fmul_rn(v, v));
        }
    } else {
        float r[8];
#pragma unroll
        for (int j = 0; j < 8; ++j) {
            float v = xb[(size_t)j * N];
            r[j] = __fmul_rn(v, v);
        }
        for (int c = 8; c < C; c += 8) {
#pragma unroll
            for (int j = 0; j < 8; ++j) {
                float v = xb[(size_t)(c + j) * N];
                r[j] = __fadd_rn(r[j], __fmul_rn(v, v));
            }
        }
        res = __fadd_rn(__fadd_rn(__fadd_rn(r[0], r[1]), __fadd_rn(r[2], r[3])),
                        __fadd_rn(__fadd_rn(r[4], r[5]), __fadd_rn(r[6], r[7])));
    }
    sq[i] = res;
}

// ---------------- knn (UNCHANGED from R9) ----------------

template <int C>
__global__ __launch_bounds__(256) void knn_radix4_kernel(const float* __restrict__ x, int Ctot,
                                                         int c0, const float* __restrict__ sq,
                                                         int* __restrict__ idxout) {
    const int b = blockIdx.y;
    const int tid = threadIdx.x, wave = tid >> 6, lane = tid & 63;
    const int nbase = blockIdx.x * 16;
    __shared__ float xn[16][C];
    const float* xb = x + ((size_t)b * Ctot + c0) * N;
    for (int t = tid; t < 16 * C; t += 256) {
        int pt = t & 15, c = t >> 4;
        xn[pt][c] = xb[(size_t)c * N + nbase + pt];
    }
    __syncthreads();
    float acc[4][16];
#pragma unroll
    for (int p = 0; p < 4; ++p)
#pragma unroll
        for (int j = 0; j < 16; ++j) acc[p][j] = 0.f;
    const float* xw0 = &xn[wave * 4 + 0][0];
    const float* xw1 = &xn[wave * 4 + 1][0];
    const float* xw2 = &xn[wave * 4 + 2][0];
    const float* xw3 = &xn[wave * 4 + 3][0];
    for (int c = 0; c < C; ++c) {
        const float* row = xb + (size_t)c * N + lane;
        float xv0 = xw0[c], xv1 = xw1[c], xv2 = xw2[c], xv3 = xw3[c];
#pragma unroll
        for (int j = 0; j < 16; ++j) {
            float rv = row[j * 64];
            acc[0][j] = __fadd_rn(acc[0][j], __fmul_rn(xv0, rv));
            acc[1][j] = __fadd_rn(acc[1][j], __fmul_rn(xv1, rv));
            acc[2][j] = __fadd_rn(acc[2][j], __fmul_rn(xv2, rv));
            acc[3][j] = __fadd_rn(acc[3][j], __fmul_rn(xv3, rv));
        }
    }
    float sqm[16];
#pragma unroll
    for (int j = 0; j < 16; ++j) sqm[j] = sq[b * N + j * 64 + lane];
    const u64 ltmask = (1ull << lane) - 1ull;
#pragma unroll
    for (int p = 0; p < 4; ++p) {
        const int n = nbase + wave * 4 + p;
        const float sqn = sq[b * N + n];
        u32 key[16];
#pragma unroll
        for (int j = 0; j < 16; ++j) {
            float d = __fsub_rn(__fsub_rn(__fmul_rn(2.f, acc[p][j]), sqn), sqm[j]);
            u32 bits = __float_as_uint(d);
            if ((bits << 1) == 0) bits = 0;
            key[j] = (bits & 0x80000000u) ? ~bits : (bits | 0x80000000u);
        }
        u32 T = 0;
        for (int bpos = 31; bpos >= 0; --bpos) {
            u32 cand = T | (1u << bpos);
            int cnt = 0;
#pragma unroll
            for (int j = 0; j < 16; ++j) cnt += __popcll(__ballot(key[j] >= cand));
            if (cnt >= KNB) T = cand;
        }
        int* out = idxout + ((size_t)b * N + n) * KNB;
        int base = 0;
#pragma unroll
        for (int j = 0; j < 16; ++j) {
            u64 m = __ballot(key[j] > T);
            if (key[j] > T) out[base + __popcll(m & ltmask)] = j * 64 + lane;
            base += __popcll(m);
        }
        const int R = KNB - base;
        int eqb = 0;
#pragma unroll
        for (int j = 0; j < 16; ++j) {
            u64 m = __ballot(key[j] == T);
            int r = eqb + __popcll(m & ltmask);
            if (key[j] == T && r < R) out[base + r] = j * 64 + lane;
            eqb += __popcll(m);
        }
    }
}

// ---------------- x0 -> row-major copy ----------------

__global__ __launch_bounds__(256) void transpose3_kernel(const float* __restrict__ x,
                                                         float* __restrict__ xT) {
    int i = blockIdx.x * blockDim.x + threadIdx.x;
    if (i >= B * N) return;
    int b = i >> 10, n = i & (N - 1);
    xT[(size_t)i * 3 + 0] = x[((size_t)b * 3 + 0) * N + n];
    xT[(size_t)i * 3 + 1] = x[((size_t)b * 3 + 1) * N + n];
    xT[(size_t)i * 3 + 2] = x[((size_t)b * 3 + 2) * N + n];
}

// ---------------- row-major [B][N][CO] -> xcat col-major slice [B][c0+..][N] ----------------

__global__ __launch_bounds__(256) void transpose_rm2cm_kernel(const float* __restrict__ yR, int CO,
                                                              float* __restrict__ xcat, int c0) {
    const int nb = blockIdx.x * 64, cb = blockIdx.y * 64, b = blockIdx.z;
    const int tid = threadIdx.x;
    __shared__ float t[64][65];
    for (int i = tid; i < 64 * 64; i += 256) {
        int nn = i >> 6, cc = i & 63;
        t[nn][cc] = yR[((size_t)(b * N + nb + nn)) * CO + cb + cc];
    }
    __syncthreads();
    for (int i = tid; i < 64 * 64; i += 256) {
        int cc = i >> 6, nn = i & 63;
        xcat[((size_t)b * 256 + c0 + cb + cc) * N + nb + nn] = t[nn][cc];
    }
}

// ---------------- layer-1 edgeconv: row-major in/out + bitplane emission ----------------

template <int C, int COUT>
__global__ __launch_bounds__(COUT) void edgeconv1_kernel(
    const float* __restrict__ xR, const int* __restrict__ idx, const float* __restrict__ W,
    const float* __restrict__ aa, const float* __restrict__ ssc, const float* __restrict__ bbi,
    const float* __restrict__ pp, float* __restrict__ yR, u32* __restrict__ xss,
    u32* __restrict__ xnzs, int woff) {
    const int b = blockIdx.y, n = blockIdx.x, tid = threadIdx.x;
    __shared__ float ctr_raw[C];
    __shared__ float df[C][KNB];
    __shared__ int ids[KNB];
    const float* xb = xR + (size_t)b * N * C;
    if (tid < KNB) ids[tid] = idx[((size_t)b * N + n) * KNB + tid];
    if (tid < C) ctr_raw[tid] = xb[(size_t)n * C + tid];
    __syncthreads();
    for (int t = tid; t < C * KNB; t += COUT) {
        int c = t / KNB, k = t - c * KNB;
        df[c][k] = __fsub_rn(xb[(size_t)ids[k] * C + c], ctr_raw[c]);
    }
    __syncthreads();
    const int o = tid;
    const float* wrow = W + (size_t)o * (2 * C);
    const float as = __fmul_rn(aa[o], ssc[o]);
    const float bo = bbi[o], po = pp[o];
    float best = -3.4e38f;
    float wd[C], wc[C];
    for (int c = 0; c < C; ++c) { wd[c] = sgnf(wrow[c]); wc[c] = sgnf(wrow[C + c]); }
    for (int k = 0; k < KNB; ++k) {
        float acc = 0.f;
        for (int c = 0; c < C; ++c) acc = __fadd_rn(acc, __fmul_rn(df[c][k], wd[c]));
        for (int c = 0; c < C; ++c) acc = __fadd_rn(acc, __fmul_rn(ctr_raw[c], wc[c]));
        float y = __fadd_rn(__fmul_rn(acc, as), bo);
        y = y > 0.f ? y : __fmul_rn(po, y);
        best = fmaxf(best, y);
    }
    yR[((size_t)b * N + n) * COUT + o] = best;
    u64 bs = __ballot(best < 0.f);
    u64 bnz = __ballot(best != 0.f);
    if ((tid & 63) == 0) {
        int w = woff + (tid >> 5);
        xss[(size_t)(b * 16 + w) * N + n] = (u32)bs;
        xss[(size_t)(b * 16 + w + 1) * N + n] = (u32)(bs >> 32);
        xnzs[(size_t)(b * 16 + w) * N + n] = (u32)bnz;
        xnzs[(size_t)(b * 16 + w + 1) * N + n] = (u32)(bnz >> 32);
    }
}

// ---------------- ternary weight pack (UNCHANGED) ----------------

__global__ __launch_bounds__(256) void pack_rows_kernel(const float* __restrict__ src, int rows,
                                                        int cols, u32* __restrict__ s,
                                                        u32* __restrict__ nz) {
    int i = blockIdx.x * blockDim.x + threadIdx.x;
    int wpr = cols >> 5;
    if (i >= rows * wpr) return;
    int r = i / wpr, w = i - r * wpr;
    const float* p = src + (size_t)r * cols + (size_t)w * 32;
    u32 sb = 0, nb = 0;
    for (int j = 0; j < 32; ++j) {
        float v = p[j];
        if (v < 0.f) sb |= (1u << j);
        if (v != 0.f) nb |= (1u << j);
    }
    s[i] = sb;
    nz[i] = nb;
}

// ---------------- binarized edgeconv: row-major gather, coalesced out + bitplanes ----------------

template <int C, int COUT, bool WRITEF>
__global__ __launch_bounds__(COUT) void edgeconv_bin2_kernel(
    const float* __restrict__ xR, const int* __restrict__ idx, const u32* __restrict__ wsm,
    const u32* __restrict__ wnzm, const float* __restrict__ aa, const float* __restrict__ ssc,
    const float* __restrict__ bbi, const float* __restrict__ pp, float* __restrict__ yR,
    u32* __restrict__ xss, u32* __restrict__ xnzs, int woff) {
    constexpr int W = C / 32;
    const int b = blockIdx.y, n = blockIdx.x, tid = threadIdx.x;
    __shared__ float ctr_raw[C];
    __shared__ int ids[KNB];
    __shared__ u32 ctr_s[W], ctr_nz[W];
    __shared__ u32 dfs[KNB][W], dfnz[KNB][W];
    const float* xb = xR + (size_t)b * N * C;
    if (tid < KNB) ids[tid] = idx[((size_t)b * N + n) * KNB + tid];
    if (tid < C) {
        float v = xb[(size_t)n * C + tid];
        ctr_raw[tid] = v;
        u64 bs = __ballot(v < 0.f);
        u64 bnz = __ballot(v != 0.f);
        if ((tid & 63) == 0) {
            int wb = tid >> 5;
            ctr_s[wb] = (u32)bs;       ctr_s[wb + 1] = (u32)(bs >> 32);
            ctr_nz[wb] = (u32)bnz;     ctr_nz[wb + 1] = (u32)(bnz >> 32);
        }
    }
    __syncthreads();
    for (int t = tid; t < KNB * C; t += COUT) {
        int k = t / C, c = t - k * C;
        float v = __fsub_rn(xb[(size_t)ids[k] * C + c], ctr_raw[c]);
        u64 bs = __ballot(v < 0.f);
        u64 bnz = __ballot(v != 0.f);
        if ((c & 63) == 0) {
            int wb = c >> 5;
            dfs[k][wb] = (u32)bs;      dfs[k][wb + 1] = (u32)(bs >> 32);
            dfnz[k][wb] = (u32)bnz;    dfnz[k][wb + 1] = (u32)(bnz >> 32);
        }
    }
    __syncthreads();
    const int o = tid;
    const u32* wsrow = wsm + (size_t)o * 2 * W;
    const u32* wnzrow = wnzm + (size_t)o * 2 * W;
    u32 wds[W], wdnz[W], wcs[W], wcnz[W];
#pragma unroll
    for (int w = 0; w < W; ++w) {
        wds[w] = wsrow[w];      wcs[w] = wsrow[W + w];
        wdnz[w] = wnzrow[w];    wcnz[w] = wnzrow[W + w];
    }
    int cdot = 0;
#pragma unroll
    for (int w = 0; w < W; ++w) {
        u32 nzb = ctr_nz[w] & wcnz[w];
        u32 neg = (ctr_s[w] ^ wcs[w]) & nzb;
        cdot += __popc(nzb) - 2 * __popc(neg);
    }
    const float as = __fmul_rn(aa[o], ssc[o]);
    const float bo = bbi[o], po = pp[o];
    float best = -3.4e38f;
    for (int k = 0; k < KNB; ++k) {
        int dot = cdot;
#pragma unroll
        for (int w = 0; w < W; ++w) {
            u32 nzb = dfnz[k][w] & wdnz[w];
            u32 neg = (dfs[k][w] ^ wds[w]) & nzb;
            dot += __popc(nzb) - 2 * __popc(neg);
        }
        float y = __fadd_rn(__fmul_rn((float)dot, as), bo);
        y = y > 0.f ? y : __fmul_rn(po, y);
        best = fmaxf(best, y);
    }
    if (WRITEF) yR[((size_t)b * N + n) * COUT + o] = best;
    u64 bs = __ballot(best < 0.f);
    u64 bnz = __ballot(best != 0.f);
    if ((tid & 63) == 0) {
        int w = woff + (tid >> 5);
        xss[(size_t)(b * 16 + w) * N + n] = (u32)bs;
        xss[(size_t)(b * 16 + w + 1) * N + n] = (u32)(bs >> 32);
        xnzs[(size_t)(b * 16 + w) * N + n] = (u32)bnz;
        xnzs[(size_t)(b * 16 + w + 1) * N + n] = (u32)(bnz >> 32);
    }
}

// ---------------- conv1d bitplane popcount + fused pooling (UNCHANGED) ----------------

__global__ __launch_bounds__(256) void conv1d_bin_pool_kernel(
    const u32* __restrict__ xs, const u32* __restrict__ xnz, const u32* __restrict__ w5s,
    const u32* __restrict__ w5nz, const float* __restrict__ aa, const float* __restrict__ ssc,
    const float* __restrict__ bbi, const float* __restrict__ pp, float* __restrict__ pmax,
    float* __restrict__ psum) {
    const int b = blockIdx.y;
    const int otile = blockIdx.x & 3;
    const int nq = blockIdx.x >> 2;
    const int tid = threadIdx.x;
    const int o = otile * 256 + tid;
    __shared__ u32 shs[128][20];
    __shared__ u32 shnz[128][20];
    u32 ws[16], wnz[16];
#pragma unroll
    for (int w = 0; w < 16; ++w) {
        ws[w] = w5s[(size_t)o * 16 + w];
        wnz[w] = w5nz[(size_t)o * 16 + w];
    }
    const float as = __fmul_rn(aa[o], ssc[o]);
    const float bo = bbi[o], po = pp[o];
    float m = -3.4e38f, sum = 0.f;
    for (int half = 0; half < 2; ++half) {
        const int nbase = nq * 256 + half * 128;
        __syncthreads();
        for (int t = tid; t < 16 * 128; t += 256) {
            int w = t >> 7, nl = t & 127;
            shs[nl][w] = xs[((size_t)b * 16 + w) * N + nbase + nl];
            shnz[nl][w] = xnz[((size_t)b * 16 + w) * N + nbase + nl];
        }
        __syncthreads();
        for (int nl = 0; nl < 128; ++nl) {
            int dot = 0;
#pragma unroll
            for (int w = 0; w < 16; ++w) {
                u32 nzb = shnz[nl][w] & wnz[w];
                u32 neg = (shs[nl][w] ^ ws[w]) & nzb;
                dot += __popc(nzb) - 2 * __popc(neg);
            }
            float y = __fadd_rn(__fmul_rn((float)dot, as), bo);
            y = y > 0.f ? y : __fmul_rn(po, y);
            m = fmaxf(m, y);
            sum = __fadd_rn(sum, y);
        }
    }
    pmax[((size_t)b * 1024 + o) * 4 + nq] = m;
    psum[((size_t)b * 1024 + o) * 4 + nq] = sum;
}

__global__ __launch_bounds__(256) void pool_reduce_kernel(const float* __restrict__ pmax,
                                                          const float* __restrict__ psum,
                                                          float* __restrict__ pooled) {
    int i = blockIdx.x * blockDim.x + threadIdx.x;
    if (i >= B * 1024) return;
    int b = i >> 10, o = i & 1023;
    const float* pm = pmax + (size_t)i * 4;
    const float* ps = psum + (size_t)i * 4;
    float m = -3.4e38f, s = 0.f;
    for (int t = 0; t < 4; ++t) { m = fmaxf(m, pm[t]); s = __fadd_rn(s, ps[t]); }
    pooled[(size_t)b * 2048 + o] = m;
    pooled[(size_t)b * 2048 + 1024 + o] = __fmul_rn(s, (1.f / 1024.f));
}

// ---------------- heads (UNCHANGED) ----------------

__global__ __launch_bounds__(512) void lin1_kernel(const float* __restrict__ xin,
                                                   const float* __restrict__ W,
                                                   const float* __restrict__ aa,
                                                   const float* __restrict__ ssc,
                                                   const float* __restrict__ bbi,
                                                   const float* __restrict__ pp,
                                                   float* __restrict__ out) {
    int b = blockIdx.x, tid = threadIdx.x;
    __shared__ float sx[2048];
    for (int c = tid; c < 2048; c += 512) sx[c] = sgnf(xin[b * 2048 + c]);
    __syncthreads();
    int o = tid;
    const float* wrow = W + (size_t)o * 2048;
    float acc = 0.f;
    for (int c = 0; c < 2048; ++c) acc = fmaf(sx[c], sgnf(wrow[c]), acc);
    float y = __fadd_rn(__fmul_rn(acc, __fmul_rn(aa[o], ssc[o])), bbi[o]);
    out[b * 512 + o] = y > 0.f ? y : __fmul_rn(pp[o], y);
}

__global__ __launch_bounds__(256) void lin2_kernel(const float* __restrict__ xin,
                                                   const float* __restrict__ W,
                                                   const float* __restrict__ aa,
                                                   const float* __restrict__ ssc,
                                                   const float* __restrict__ bbi,
                                                   const float* __restrict__ pp,
                                                   float* __restrict__ out) {
    int b = blockIdx.x, tid = threadIdx.x;
    __shared__ float sx[512];
    for (int c = tid; c < 512; c += 256) sx[c] = sgnf(xin[b * 512 + c]);
    __syncthreads();
    int o = tid;
    const float* wrow = W + (size_t)o * 512;
    float acc = 0.f;
    for (int c = 0; c < 512; ++c) acc = fmaf(sx[c], sgnf(wrow[c]), acc);
    float y = __fadd_rn(__fmul_rn(acc, __fmul_rn(aa[o], ssc[o])), bbi[o]);
    out[b * 256 + o] = y > 0.f ? y : __fmul_rn(pp[o], y);
}

__global__ __launch_bounds__(64) void lin3_kernel(const float* __restrict__ xin,
                                                  const float* __restrict__ W,
                                                  const float* __restrict__ ssc,
                                                  const float* __restrict__ bbi,
                                                  float* __restrict__ out) {
    int b = blockIdx.x, j = threadIdx.x;
    if (j >= 40) return;
    const float* wrow = W + j * 256;
    const float* xb = xin + b * 256;
    double acc = 0.0;
    for (int c = 0; c < 256; ++c) acc = fma((double)xb[c], (double)wrow[c], acc);
    out[b * 40 + j] = __fadd_rn(__fmul_rn((float)acc, ssc[j]), bbi[j]);
}

extern "C" void kernel_launch(void* const* d_in, const int* in_sizes, int n_in, void* d_out,
                              int out_size, void* d_ws, size_t ws_size, hipStream_t stream) {
    float* outp = (float*)d_out;
    auto sentinel = [&](float code) {
        sentinel_kernel<<<(640 + 255) / 256, 256, 0, stream>>>(outp, 640, code * 1.0e6f);
    };
    if (n_in != 39) { sentinel(1.f); return; }
    static const int expect[39] = {
        16 * 3 * 1024,
        64 * 6, 64, 64, 64, 64,
        64 * 128, 64, 64, 64, 64,
        128 * 128, 128, 128, 128, 128,
        256 * 256, 256, 256, 256, 256,
        1024 * 512, 1024, 1024, 1024, 1024,
        512 * 2048, 512, 512, 512, 512,
        256 * 512, 256, 256, 256, 256,
        40 * 256, 40, 40
    };
    for (int i = 0; i < 39; ++i)
        if (in_sizes[i] != expect[i]) { sentinel(2.f); return; }
    if (out_size != 640) { sentinel(3.f); return; }

    const float* x0 = (const float*)d_in[0];
    const float *w1 = (const float*)d_in[1], *a1 = (const float*)d_in[2],
                *s1 = (const float*)d_in[3], *b1 = (const float*)d_in[4],
                *p1 = (const float*)d_in[5];
    const float *a2 = (const float*)d_in[7], *s2 = (const float*)d_in[8],
                *b2 = (const float*)d_in[9], *p2 = (const float*)d_in[10];
    const float *a3 = (const float*)d_in[12], *s3 = (const float*)d_in[13],
                *b3 = (const float*)d_in[14], *p3 = (const float*)d_in[15];
    const float *a4 = (const float*)d_in[17], *s4 = (const float*)d_in[18],
                *b4 = (const float*)d_in[19], *p4 = (const float*)d_in[20];
    const float *a5 = (const float*)d_in[22], *s5 = (const float*)d_in[23],
                *b5 = (const float*)d_in[24], *p5 = (const float*)d_in[25];
    const float *w2 = (const float*)d_in[6], *w3 = (const float*)d_in[11],
                *w4 = (const float*)d_in[16], *w5 = (const float*)d_in[21];
    const float *wl1 = (const float*)d_in[26], *al1 = (const float*)d_in[27],
                *sl1 = (const float*)d_in[28], *bl1 = (const float*)d_in[29],
                *pl1 = (const float*)d_in[30];
    const float *wl2 = (const float*)d_in[31], *al2 = (const float*)d_in[32],
                *sl2 = (const float*)d_in[33], *bl2 = (const float*)d_in[34],
                *pl2 = (const float*)d_in[35];
    const float *wl3 = (const float*)d_in[36], *sl3 = (const float*)d_in[37],
                *bl3 = (const float*)d_in[38];

    char* ws = (char*)d_ws;
    size_t off = 0;
    auto alloc = [&](size_t bytes) -> void* {
        void* p = ws + off;
        off += (bytes + 255) & ~(size_t)255;
        return p;
    };
    float* xcat = (float*)alloc((size_t)B * 256 * N * 4);  // col-major x1,x2,x3 for knn/sq
    float* yA = (float*)alloc((size_t)B * N * 128 * 4);    // row-major: L1 out (64), L3 out (128)
    float* yB = (float*)alloc((size_t)B * N * 64 * 4);     // row-major: L2 out (64)
    float* x0R = (float*)alloc((size_t)B * N * 3 * 4);
    int* idxb = (int*)alloc((size_t)B * N * KNB * 4);
    float* sqb = (float*)alloc((size_t)B * N * 4);
    u32* w2s_ = (u32*)alloc(64 * 4 * 4);     u32* w2nz_ = (u32*)alloc(64 * 4 * 4);
    u32* w3s_ = (u32*)alloc(128 * 4 * 4);    u32* w3nz_ = (u32*)alloc(128 * 4 * 4);
    u32* w4s_ = (u32*)alloc(256 * 8 * 4);    u32* w4nz_ = (u32*)alloc(256 * 8 * 4);
    u32* w5s_ = (u32*)alloc(1024 * 16 * 4);  u32* w5nz_ = (u32*)alloc(1024 * 16 * 4);
    u32* xss = (u32*)alloc((size_t)B * 16 * N * 4);
    u32* xnzs = (u32*)alloc((size_t)B * 16 * N * 4);
    float* pmax = (float*)alloc((size_t)B * 1024 * 4 * 4);
    float* psum = (float*)alloc((size_t)B * 1024 * 4 * 4);
    float* pooled = (float*)alloc((size_t)B * 2048 * 4);
    float* l1o = (float*)alloc((size_t)B * 512 * 4);
    float* l2o = (float*)alloc((size_t)B * 256 * 4);
    if (off > ws_size) { sentinel(4.f); return; }

    pack_rows_kernel<<<1, 256, 0, stream>>>(w2, 64, 128, w2s_, w2nz_);
    pack_rows_kernel<<<2, 256, 0, stream>>>(w3, 128, 128, w3s_, w3nz_);
    pack_rows_kernel<<<8, 256, 0, stream>>>(w4, 256, 256, w4s_, w4nz_);
    pack_rows_kernel<<<64, 256, 0, stream>>>(w5, 1024, 512, w5s_, w5nz_);

    dim3 gnb(N, B);
    dim3 gknn(N / 16, B);
    const int npt = (B * N + 255) / 256;
    // ---- layer 1: knn on x0 (C=3, col-major); edgeconv row-major ----
    sq_np_kernel<3><<<npt, 256, 0, stream>>>(x0, 3, 0, sqb);
    transpose3_kernel<<<npt, 256, 0, stream>>>(x0, x0R);
    knn_radix4_kernel<3><<<gknn, 256, 0, stream>>>(x0, 3, 0, sqb, idxb);
    edgeconv1_kernel<3, 64>
        <<<gnb, 64, 0, stream>>>(x0R, idxb, w1, a1, s1, b1, p1, yA, xss, xnzs, 0);
    transpose_rm2cm_kernel<<<dim3(16, 1, B), 256, 0, stream>>>(yA, 64, xcat, 0);
    // ---- layer 2: knn on x1 (xcat c0=0); edgeconv gathers yA -> yB ----
    sq_np_kernel<64><<<npt, 256, 0, stream>>>(xcat, 256, 0, sqb);
    knn_radix4_kernel<64><<<gknn, 256, 0, stream>>>(xcat, 256, 0, sqb, idxb);
    edgeconv_bin2_kernel<64, 64, true>
        <<<gnb, 64, 0, stream>>>(yA, idxb, w2s_, w2nz_, a2, s2, b2, p2, yB, xss, xnzs, 2);
    transpose_rm2cm_kernel<<<dim3(16, 1, B), 256, 0, stream>>>(yB, 64, xcat, 64);
    // ---- layer 3: knn on x2 (c0=64); edgeconv gathers yB -> yA (128ch) ----
    sq_np_kernel<64><<<npt, 256, 0, stream>>>(xcat, 256, 64, sqb);
    knn_radix4_kernel<64><<<gknn, 256, 0, stream>>>(xcat, 256, 64, sqb, idxb);
    edgeconv_bin2_kernel<64, 128, true>
        <<<gnb, 128, 0, stream>>>(yB, idxb, w3s_, w3nz_, a3, s3, b3, p3, yA, xss, xnzs, 4);
    transpose_rm2cm_kernel<<<dim3(16, 2, B), 256, 0, stream>>>(yA, 128, xcat, 128);
    // ---- layer 4: knn on x3 (c0=128); edgeconv gathers yA, emits bitplanes only ----
    sq_np_kernel<128><<<npt, 256, 0, stream>>>(xcat, 256, 128, sqb);
    knn_radix4_kernel<128><<<gknn, 256, 0, stream>>>(xcat, 256, 128, sqb, idxb);
    edgeconv_bin2_kernel<128, 256, false>
        <<<gnb, 256, 0, stream>>>(yA, idxb, w4s_, w4nz_, a4, s4, b4, p4, nullptr, xss, xnzs, 8);
    // ---- conv1d + pooling + heads ----
    conv1d_bin_pool_kernel<<<dim3(16, B), 256, 0, stream>>>(xss, xnzs, w5s_, w5nz_, a5, s5, b5,
                                                            p5, pmax, psum);
    pool_reduce_kernel<<<(B * 1024 + 255) / 256, 256, 0, stream>>>(pmax, psum, pooled);
    lin1_kernel<<<B, 512, 0, stream>>>(pooled, wl1, al1, sl1, bl1, pl1, l1o);
    lin2_kernel<<<B, 256, 0, stream>>>(l1o, wl2, al2, sl2, bl2, pl2, l2o);
    lin3_kernel<<<B, 64, 0, stream>>>(l2o, wl3, sl3, bl3, outp);
}

// Round 11
// 654.295 us; speedup vs baseline: 5.6223x; 1.1910x over previous
//
#include <hip/hip_runtime.h>
#include <math.h>

#define B 16
#define N 1024
#define KNB 20

typedef unsigned int u32;
typedef unsigned long long u64;

__device__ __forceinline__ float sgnf(float v) {
    return (v > 0.f) ? 1.f : ((v < 0.f) ? -1.f : 0.f);
}

__global__ __launch_bounds__(256) void sentinel_kernel(float* __restrict__ out, int n, float v) {
    int i = blockIdx.x * blockDim.x + threadIdx.x;
    if (i < n) out[i] = v;
}

// ---------------- np-exact sq (UNCHANGED arithmetic) ----------------

template <int C>
__global__ __launch_bounds__(256) void sq_np_kernel(const float* __restrict__ x, int Ctot, int c0,
                                                    float* __restrict__ sq) {
    int i = blockIdx.x * blockDim.x + threadIdx.x;
    if (i >= B * N) return;
    int b = i >> 10, n = i & (N - 1);
    const float* xb = x + ((size_t)b * Ctot + c0) * N + n;
    float res;
    if (C < 8) {
        float v0 = xb[0];
        res = __fmul_rn(v0, v0);
        for (int c = 1; c < C; ++c) {
            float v = xb[(size_t)c * N];
            res = __fadd_rn(res, __fmul_rn(v, v));
        }
    } else {
        float r[8];
#pragma unroll
        for (int j = 0; j < 8; ++j) {
            float v = xb[(size_t)j * N];
            r[j] = __fmul_rn(v, v);
        }
        for (int c = 8; c < C; c += 8) {
#pragma unroll
            for (int j = 0; j < 8; ++j) {
                float v = xb[(size_t)(c + j) * N];
                r[j] = __fadd_rn(r[j], __fmul_rn(v, v));
            }
        }
        res = __fadd_rn(__fadd_rn(__fadd_rn(r[0], r[1]), __fadd_rn(r[2], r[3])),
                        __fadd_rn(__fadd_rn(r[4], r[5]), __fadd_rn(r[6], r[7])));
    }
    sq[i] = res;
}

// ---------------- knn (UNCHANGED from R9) ----------------

template <int C>
__global__ __launch_bounds__(256) void knn_radix4_kernel(const float* __restrict__ x, int Ctot,
                                                         int c0, const float* __restrict__ sq,
                                                         int* __restrict__ idxout) {
    const int b = blockIdx.y;
    const int tid = threadIdx.x, wave = tid >> 6, lane = tid & 63;
    const int nbase = blockIdx.x * 16;
    __shared__ float xn[16][C];
    const float* xb = x + ((size_t)b * Ctot + c0) * N;
    for (int t = tid; t < 16 * C; t += 256) {
        int pt = t & 15, c = t >> 4;
        xn[pt][c] = xb[(size_t)c * N + nbase + pt];
    }
    __syncthreads();
    float acc[4][16];
#pragma unroll
    for (int p = 0; p < 4; ++p)
#pragma unroll
        for (int j = 0; j < 16; ++j) acc[p][j] = 0.f;
    const float* xw0 = &xn[wave * 4 + 0][0];
    const float* xw1 = &xn[wave * 4 + 1][0];
    const float* xw2 = &xn[wave * 4 + 2][0];
    const float* xw3 = &xn[wave * 4 + 3][0];
    for (int c = 0; c < C; ++c) {
        const float* row = xb + (size_t)c * N + lane;
        float xv0 = xw0[c], xv1 = xw1[c], xv2 = xw2[c], xv3 = xw3[c];
#pragma unroll
        for (int j = 0; j < 16; ++j) {
            float rv = row[j * 64];
            acc[0][j] = __fadd_rn(acc[0][j], __fmul_rn(xv0, rv));
            acc[1][j] = __fadd_rn(acc[1][j], __fmul_rn(xv1, rv));
            acc[2][j] = __fadd_rn(acc[2][j], __fmul_rn(xv2, rv));
            acc[3][j] = __fadd_rn(acc[3][j], __fmul_rn(xv3, rv));
        }
    }
    float sqm[16];
#pragma unroll
    for (int j = 0; j < 16; ++j) sqm[j] = sq[b * N + j * 64 + lane];
    const u64 ltmask = (1ull << lane) - 1ull;
#pragma unroll
    for (int p = 0; p < 4; ++p) {
        const int n = nbase + wave * 4 + p;
        const float sqn = sq[b * N + n];
        u32 key[16];
#pragma unroll
        for (int j = 0; j < 16; ++j) {
            float d = __fsub_rn(__fsub_rn(__fmul_rn(2.f, acc[p][j]), sqn), sqm[j]);
            u32 bits = __float_as_uint(d);
            if ((bits << 1) == 0) bits = 0;
            key[j] = (bits & 0x80000000u) ? ~bits : (bits | 0x80000000u);
        }
        u32 T = 0;
        for (int bpos = 31; bpos >= 0; --bpos) {
            u32 cand = T | (1u << bpos);
            int cnt = 0;
#pragma unroll
            for (int j = 0; j < 16; ++j) cnt += __popcll(__ballot(key[j] >= cand));
            if (cnt >= KNB) T = cand;
        }
        int* out = idxout + ((size_t)b * N + n) * KNB;
        int base = 0;
#pragma unroll
        for (int j = 0; j < 16; ++j) {
            u64 m = __ballot(key[j] > T);
            if (key[j] > T) out[base + __popcll(m & ltmask)] = j * 64 + lane;
            base += __popcll(m);
        }
        const int R = KNB - base;
        int eqb = 0;
#pragma unroll
        for (int j = 0; j < 16; ++j) {
            u64 m = __ballot(key[j] == T);
            int r = eqb + __popcll(m & ltmask);
            if (key[j] == T && r < R) out[base + r] = j * 64 + lane;
            eqb += __popcll(m);
        }
    }
}

// ---------------- x0 -> row-major copy ----------------

__global__ __launch_bounds__(256) void transpose3_kernel(const float* __restrict__ x,
                                                         float* __restrict__ xT) {
    int i = blockIdx.x * blockDim.x + threadIdx.x;
    if (i >= B * N) return;
    int b = i >> 10, n = i & (N - 1);
    xT[(size_t)i * 3 + 0] = x[((size_t)b * 3 + 0) * N + n];
    xT[(size_t)i * 3 + 1] = x[((size_t)b * 3 + 1) * N + n];
    xT[(size_t)i * 3 + 2] = x[((size_t)b * 3 + 2) * N + n];
}

// ---------------- row-major [B][N][CO] -> xcat col-major slice ----------------

__global__ __launch_bounds__(256) void transpose_rm2cm_kernel(const float* __restrict__ yR, int CO,
                                                              float* __restrict__ xcat, int c0) {
    const int nb = blockIdx.x * 64, cb = blockIdx.y * 64, b = blockIdx.z;
    const int tid = threadIdx.x;
    __shared__ float t[64][65];
    for (int i = tid; i < 64 * 64; i += 256) {
        int nn = i >> 6, cc = i & 63;
        t[nn][cc] = yR[((size_t)(b * N + nb + nn)) * CO + cb + cc];
    }
    __syncthreads();
    for (int i = tid; i < 64 * 64; i += 256) {
        int cc = i >> 6, nn = i & 63;
        xcat[((size_t)b * 256 + c0 + cb + cc) * N + nb + nn] = t[nn][cc];
    }
}

// ---------------- layer-1 edgeconv (np-exact) ----------------

template <int C, int COUT>
__global__ __launch_bounds__(COUT) void edgeconv1_kernel(
    const float* __restrict__ xR, const int* __restrict__ idx, const float* __restrict__ W,
    const float* __restrict__ aa, const float* __restrict__ ssc, const float* __restrict__ bbi,
    const float* __restrict__ pp, float* __restrict__ yR, u32* __restrict__ xss,
    u32* __restrict__ xnzs, int woff) {
    const int b = blockIdx.y, n = blockIdx.x, tid = threadIdx.x;
    __shared__ float ctr_raw[C];
    __shared__ float df[C][KNB];
    __shared__ int ids[KNB];
    const float* xb = xR + (size_t)b * N * C;
    if (tid < KNB) ids[tid] = idx[((size_t)b * N + n) * KNB + tid];
    if (tid < C) ctr_raw[tid] = xb[(size_t)n * C + tid];
    __syncthreads();
    for (int t = tid; t < C * KNB; t += COUT) {
        int c = t / KNB, k = t - c * KNB;
        df[c][k] = __fsub_rn(xb[(size_t)ids[k] * C + c], ctr_raw[c]);
    }
    __syncthreads();
    const int o = tid;
    const float* wrow = W + (size_t)o * (2 * C);
    const float as = __fmul_rn(aa[o], ssc[o]);
    const float bo = bbi[o], po = pp[o];
    float best = -3.4e38f;
    float wd[C], wc[C];
    for (int c = 0; c < C; ++c) { wd[c] = sgnf(wrow[c]); wc[c] = sgnf(wrow[C + c]); }
    for (int k = 0; k < KNB; ++k) {
        float acc = 0.f;
        for (int c = 0; c < C; ++c) acc = __fadd_rn(acc, __fmul_rn(df[c][k], wd[c]));
        for (int c = 0; c < C; ++c) acc = __fadd_rn(acc, __fmul_rn(ctr_raw[c], wc[c]));
        float y = __fadd_rn(__fmul_rn(acc, as), bo);
        y = y > 0.f ? y : __fmul_rn(po, y);
        best = fmaxf(best, y);
    }
    yR[((size_t)b * N + n) * COUT + o] = best;
    u64 bs = __ballot(best < 0.f);
    u64 bnz = __ballot(best != 0.f);
    if ((tid & 63) == 0) {
        int w = woff + (tid >> 5);
        xss[(size_t)(b * 16 + w) * N + n] = (u32)bs;
        xss[(size_t)(b * 16 + w + 1) * N + n] = (u32)(bs >> 32);
        xnzs[(size_t)(b * 16 + w) * N + n] = (u32)bnz;
        xnzs[(size_t)(b * 16 + w + 1) * N + n] = (u32)(bnz >> 32);
    }
}

// ---------------- ternary weight / vector pack ----------------

__global__ __launch_bounds__(256) void pack_rows_kernel(const float* __restrict__ src, int rows,
                                                        int cols, u32* __restrict__ s,
                                                        u32* __restrict__ nz) {
    int i = blockIdx.x * blockDim.x + threadIdx.x;
    int wpr = cols >> 5;
    if (i >= rows * wpr) return;
    int r = i / wpr, w = i - r * wpr;
    const float* p = src + (size_t)r * cols + (size_t)w * 32;
    u32 sb = 0, nb = 0;
    for (int j = 0; j < 32; ++j) {
        float v = p[j];
        if (v < 0.f) sb |= (1u << j);
        if (v != 0.f) nb |= (1u << j);
    }
    s[i] = sb;
    nz[i] = nb;
}

// ---------------- binarized edgeconv (UNCHANGED from R10) ----------------

template <int C, int COUT, bool WRITEF>
__global__ __launch_bounds__(COUT) void edgeconv_bin2_kernel(
    const float* __restrict__ xR, const int* __restrict__ idx, const u32* __restrict__ wsm,
    const u32* __restrict__ wnzm, const float* __restrict__ aa, const float* __restrict__ ssc,
    const float* __restrict__ bbi, const float* __restrict__ pp, float* __restrict__ yR,
    u32* __restrict__ xss, u32* __restrict__ xnzs, int woff) {
    constexpr int W = C / 32;
    const int b = blockIdx.y, n = blockIdx.x, tid = threadIdx.x;
    __shared__ float ctr_raw[C];
    __shared__ int ids[KNB];
    __shared__ u32 ctr_s[W], ctr_nz[W];
    __shared__ u32 dfs[KNB][W], dfnz[KNB][W];
    const float* xb = xR + (size_t)b * N * C;
    if (tid < KNB) ids[tid] = idx[((size_t)b * N + n) * KNB + tid];
    if (tid < C) {
        float v = xb[(size_t)n * C + tid];
        ctr_raw[tid] = v;
        u64 bs = __ballot(v < 0.f);
        u64 bnz = __ballot(v != 0.f);
        if ((tid & 63) == 0) {
            int wb = tid >> 5;
            ctr_s[wb] = (u32)bs;       ctr_s[wb + 1] = (u32)(bs >> 32);
            ctr_nz[wb] = (u32)bnz;     ctr_nz[wb + 1] = (u32)(bnz >> 32);
        }
    }
    __syncthreads();
    for (int t = tid; t < KNB * C; t += COUT) {
        int k = t / C, c = t - k * C;
        float v = __fsub_rn(xb[(size_t)ids[k] * C + c], ctr_raw[c]);
        u64 bs = __ballot(v < 0.f);
        u64 bnz = __ballot(v != 0.f);
        if ((c & 63) == 0) {
            int wb = c >> 5;
            dfs[k][wb] = (u32)bs;      dfs[k][wb + 1] = (u32)(bs >> 32);
            dfnz[k][wb] = (u32)bnz;    dfnz[k][wb + 1] = (u32)(bnz >> 32);
        }
    }
    __syncthreads();
    const int o = tid;
    const u32* wsrow = wsm + (size_t)o * 2 * W;
    const u32* wnzrow = wnzm + (size_t)o * 2 * W;
    u32 wds[W], wdnz[W], wcs[W], wcnz[W];
#pragma unroll
    for (int w = 0; w < W; ++w) {
        wds[w] = wsrow[w];      wcs[w] = wsrow[W + w];
        wdnz[w] = wnzrow[w];    wcnz[w] = wnzrow[W + w];
    }
    int cdot = 0;
#pragma unroll
    for (int w = 0; w < W; ++w) {
        u32 nzb = ctr_nz[w] & wcnz[w];
        u32 neg = (ctr_s[w] ^ wcs[w]) & nzb;
        cdot += __popc(nzb) - 2 * __popc(neg);
    }
    const float as = __fmul_rn(aa[o], ssc[o]);
    const float bo = bbi[o], po = pp[o];
    float best = -3.4e38f;
    for (int k = 0; k < KNB; ++k) {
        int dot = cdot;
#pragma unroll
        for (int w = 0; w < W; ++w) {
            u32 nzb = dfnz[k][w] & wdnz[w];
            u32 neg = (dfs[k][w] ^ wds[w]) & nzb;
            dot += __popc(nzb) - 2 * __popc(neg);
        }
        float y = __fadd_rn(__fmul_rn((float)dot, as), bo);
        y = y > 0.f ? y : __fmul_rn(po, y);
        best = fmaxf(best, y);
    }
    if (WRITEF) yR[((size_t)b * N + n) * COUT + o] = best;
    u64 bs = __ballot(best < 0.f);
    u64 bnz = __ballot(best != 0.f);
    if ((tid & 63) == 0) {
        int w = woff + (tid >> 5);
        xss[(size_t)(b * 16 + w) * N + n] = (u32)bs;
        xss[(size_t)(b * 16 + w + 1) * N + n] = (u32)(bs >> 32);
        xnzs[(size_t)(b * 16 + w) * N + n] = (u32)bnz;
        xnzs[(size_t)(b * 16 + w + 1) * N + n] = (u32)(bnz >> 32);
    }
}

// ---------------- conv1d bitplane popcount + fused pooling (UNCHANGED) ----------------

__global__ __launch_bounds__(256) void conv1d_bin_pool_kernel(
    const u32* __restrict__ xs, const u32* __restrict__ xnz, const u32* __restrict__ w5s,
    const u32* __restrict__ w5nz, const float* __restrict__ aa, const float* __restrict__ ssc,
    const float* __restrict__ bbi, const float* __restrict__ pp, float* __restrict__ pmax,
    float* __restrict__ psum) {
    const int b = blockIdx.y;
    const int otile = blockIdx.x & 3;
    const int nq = blockIdx.x >> 2;
    const int tid = threadIdx.x;
    const int o = otile * 256 + tid;
    __shared__ u32 shs[128][20];
    __shared__ u32 shnz[128][20];
    u32 ws[16], wnz[16];
#pragma unroll
    for (int w = 0; w < 16; ++w) {
        ws[w] = w5s[(size_t)o * 16 + w];
        wnz[w] = w5nz[(size_t)o * 16 + w];
    }
    const float as = __fmul_rn(aa[o], ssc[o]);
    const float bo = bbi[o], po = pp[o];
    float m = -3.4e38f, sum = 0.f;
    for (int half = 0; half < 2; ++half) {
        const int nbase = nq * 256 + half * 128;
        __syncthreads();
        for (int t = tid; t < 16 * 128; t += 256) {
            int w = t >> 7, nl = t & 127;
            shs[nl][w] = xs[((size_t)b * 16 + w) * N + nbase + nl];
            shnz[nl][w] = xnz[((size_t)b * 16 + w) * N + nbase + nl];
        }
        __syncthreads();
        for (int nl = 0; nl < 128; ++nl) {
            int dot = 0;
#pragma unroll
            for (int w = 0; w < 16; ++w) {
                u32 nzb = shnz[nl][w] & wnz[w];
                u32 neg = (shs[nl][w] ^ ws[w]) & nzb;
                dot += __popc(nzb) - 2 * __popc(neg);
            }
            float y = __fadd_rn(__fmul_rn((float)dot, as), bo);
            y = y > 0.f ? y : __fmul_rn(po, y);
            m = fmaxf(m, y);
            sum = __fadd_rn(sum, y);
        }
    }
    pmax[((size_t)b * 1024 + o) * 4 + nq] = m;
    psum[((size_t)b * 1024 + o) * 4 + nq] = sum;
}

__global__ __launch_bounds__(256) void pool_reduce_kernel(const float* __restrict__ pmax,
                                                          const float* __restrict__ psum,
                                                          float* __restrict__ pooled) {
    int i = blockIdx.x * blockDim.x + threadIdx.x;
    if (i >= B * 1024) return;
    int b = i >> 10, o = i & 1023;
    const float* pm = pmax + (size_t)i * 4;
    const float* ps = psum + (size_t)i * 4;
    float m = -3.4e38f, s = 0.f;
    for (int t = 0; t < 4; ++t) { m = fmaxf(m, pm[t]); s = __fadd_rn(s, ps[t]); }
    pooled[(size_t)b * 2048 + o] = m;
    pooled[(size_t)b * 2048 + 1024 + o] = __fmul_rn(s, (1.f / 1024.f));
}

// pack pooled (B x 2048) into ternary bitplanes: B x 64 words
__global__ __launch_bounds__(256) void pack_pooled_kernel(const float* __restrict__ pooled,
                                                          u32* __restrict__ s,
                                                          u32* __restrict__ nz) {
    int i = blockIdx.x * blockDim.x + threadIdx.x;
    if (i >= B * 64) return;
    const float* p = pooled + (size_t)i * 32;
    u32 sb = 0, nb = 0;
    for (int j = 0; j < 32; ++j) {
        float v = p[j];
        if (v < 0.f) sb |= (1u << j);
        if (v != 0.f) nb |= (1u << j);
    }
    s[i] = sb;
    nz[i] = nb;
}

// ---------------- bitpacked lin1: 512 outs/b, 2048 ins (64 words) ----------------
// grid (2, B) x 256; emits l1 sign/nz bitplanes (16 words/b) for lin2.
__global__ __launch_bounds__(256) void lin1_bin_kernel(
    const u32* __restrict__ xs, const u32* __restrict__ xnz, const u32* __restrict__ wls,
    const u32* __restrict__ wlnz, const float* __restrict__ aa, const float* __restrict__ ssc,
    const float* __restrict__ bbi, const float* __restrict__ pp, u32* __restrict__ l1s,
    u32* __restrict__ l1nz) {
    const int b = blockIdx.y, otile = blockIdx.x, tid = threadIdx.x;
    const int o = otile * 256 + tid;
    __shared__ u32 sxs[64], sxnz[64];
    if (tid < 64) { sxs[tid] = xs[b * 64 + tid]; sxnz[tid] = xnz[b * 64 + tid]; }
    __syncthreads();
    const u32* wsr = wls + (size_t)o * 64;
    const u32* wnzr = wlnz + (size_t)o * 64;
    int dot = 0;
#pragma unroll
    for (int w = 0; w < 64; ++w) {
        u32 nzb = sxnz[w] & wnzr[w];
        u32 neg = (sxs[w] ^ wsr[w]) & nzb;
        dot += __popc(nzb) - 2 * __popc(neg);
    }
    float y = __fadd_rn(__fmul_rn((float)dot, __fmul_rn(aa[o], ssc[o])), bbi[o]);
    y = y > 0.f ? y : __fmul_rn(pp[o], y);
    u64 bs = __ballot(y < 0.f);
    u64 bnz = __ballot(y != 0.f);
    if ((tid & 63) == 0) {
        int w = otile * 8 + (tid >> 5);
        l1s[b * 16 + w] = (u32)bs;       l1s[b * 16 + w + 1] = (u32)(bs >> 32);
        l1nz[b * 16 + w] = (u32)bnz;     l1nz[b * 16 + w + 1] = (u32)(bnz >> 32);
    }
}

// ---------------- bitpacked lin2: 256 outs/b, 512 ins (16 words); float out ----------------
__global__ __launch_bounds__(256) void lin2_bin_kernel(
    const u32* __restrict__ xs, const u32* __restrict__ xnz, const u32* __restrict__ wls,
    const u32* __restrict__ wlnz, const float* __restrict__ aa, const float* __restrict__ ssc,
    const float* __restrict__ bbi, const float* __restrict__ pp, float* __restrict__ out) {
    const int b = blockIdx.x, o = threadIdx.x;
    __shared__ u32 sxs[16], sxnz[16];
    if (o < 16) { sxs[o] = xs[b * 16 + o]; sxnz[o] = xnz[b * 16 + o]; }
    __syncthreads();
    const u32* wsr = wls + (size_t)o * 16;
    const u32* wnzr = wlnz + (size_t)o * 16;
    int dot = 0;
#pragma unroll
    for (int w = 0; w < 16; ++w) {
        u32 nzb = sxnz[w] & wnzr[w];
        u32 neg = (sxs[w] ^ wsr[w]) & nzb;
        dot += __popc(nzb) - 2 * __popc(neg);
    }
    float y = __fadd_rn(__fmul_rn((float)dot, __fmul_rn(aa[o], ssc[o])), bbi[o]);
    out[b * 256 + o] = y > 0.f ? y : __fmul_rn(pp[o], y);
}

__global__ __launch_bounds__(64) void lin3_kernel(const float* __restrict__ xin,
                                                  const float* __restrict__ W,
                                                  const float* __restrict__ ssc,
                                                  const float* __restrict__ bbi,
                                                  float* __restrict__ out) {
    int b = blockIdx.x, j = threadIdx.x;
    if (j >= 40) return;
    const float* wrow = W + j * 256;
    const float* xb = xin + b * 256;
    double acc = 0.0;
    for (int c = 0; c < 256; ++c) acc = fma((double)xb[c], (double)wrow[c], acc);
    out[b * 40 + j] = __fadd_rn(__fmul_rn((float)acc, ssc[j]), bbi[j]);
}

extern "C" void kernel_launch(void* const* d_in, const int* in_sizes, int n_in, void* d_out,
                              int out_size, void* d_ws, size_t ws_size, hipStream_t stream) {
    float* outp = (float*)d_out;
    auto sentinel = [&](float code) {
        sentinel_kernel<<<(640 + 255) / 256, 256, 0, stream>>>(outp, 640, code * 1.0e6f);
    };
    if (n_in != 39) { sentinel(1.f); return; }
    static const int expect[39] = {
        16 * 3 * 1024,
        64 * 6, 64, 64, 64, 64,
        64 * 128, 64, 64, 64, 64,
        128 * 128, 128, 128, 128, 128,
        256 * 256, 256, 256, 256, 256,
        1024 * 512, 1024, 1024, 1024, 1024,
        512 * 2048, 512, 512, 512, 512,
        256 * 512, 256, 256, 256, 256,
        40 * 256, 40, 40
    };
    for (int i = 0; i < 39; ++i)
        if (in_sizes[i] != expect[i]) { sentinel(2.f); return; }
    if (out_size != 640) { sentinel(3.f); return; }

    const float* x0 = (const float*)d_in[0];
    const float *w1 = (const float*)d_in[1], *a1 = (const float*)d_in[2],
                *s1 = (const float*)d_in[3], *b1 = (const float*)d_in[4],
                *p1 = (const float*)d_in[5];
    const float *a2 = (const float*)d_in[7], *s2 = (const float*)d_in[8],
                *b2 = (const float*)d_in[9], *p2 = (const float*)d_in[10];
    const float *a3 = (const float*)d_in[12], *s3 = (const float*)d_in[13],
                *b3 = (const float*)d_in[14], *p3 = (const float*)d_in[15];
    const float *a4 = (const float*)d_in[17], *s4 = (const float*)d_in[18],
                *b4 = (const float*)d_in[19], *p4 = (const float*)d_in[20];
    const float *a5 = (const float*)d_in[22], *s5 = (const float*)d_in[23],
                *b5 = (const float*)d_in[24], *p5 = (const float*)d_in[25];
    const float *w2 = (const float*)d_in[6], *w3 = (const float*)d_in[11],
                *w4 = (const float*)d_in[16], *w5 = (const float*)d_in[21];
    const float *wl1 = (const float*)d_in[26], *al1 = (const float*)d_in[27],
                *sl1 = (const float*)d_in[28], *bl1 = (const float*)d_in[29],
                *pl1 = (const float*)d_in[30];
    const float *wl2 = (const float*)d_in[31], *al2 = (const float*)d_in[32],
                *sl2 = (const float*)d_in[33], *bl2 = (const float*)d_in[34],
                *pl2 = (const float*)d_in[35];
    const float *wl3 = (const float*)d_in[36], *sl3 = (const float*)d_in[37],
                *bl3 = (const float*)d_in[38];

    char* ws = (char*)d_ws;
    size_t off = 0;
    auto alloc = [&](size_t bytes) -> void* {
        void* p = ws + off;
        off += (bytes + 255) & ~(size_t)255;
        return p;
    };
    float* xcat = (float*)alloc((size_t)B * 256 * N * 4);
    float* yA = (float*)alloc((size_t)B * N * 128 * 4);
    float* yB = (float*)alloc((size_t)B * N * 64 * 4);
    float* x0R = (float*)alloc((size_t)B * N * 3 * 4);
    int* idxb = (int*)alloc((size_t)B * N * KNB * 4);
    float* sqb = (float*)alloc((size_t)B * N * 4);
    u32* w2s_ = (u32*)alloc(64 * 4 * 4);     u32* w2nz_ = (u32*)alloc(64 * 4 * 4);
    u32* w3s_ = (u32*)alloc(128 * 4 * 4);    u32* w3nz_ = (u32*)alloc(128 * 4 * 4);
    u32* w4s_ = (u32*)alloc(256 * 8 * 4);    u32* w4nz_ = (u32*)alloc(256 * 8 * 4);
    u32* w5s_ = (u32*)alloc(1024 * 16 * 4);  u32* w5nz_ = (u32*)alloc(1024 * 16 * 4);
    u32* wl1s_ = (u32*)alloc(512 * 64 * 4);  u32* wl1nz_ = (u32*)alloc(512 * 64 * 4);
    u32* wl2s_ = (u32*)alloc(256 * 16 * 4);  u32* wl2nz_ = (u32*)alloc(256 * 16 * 4);
    u32* xss = (u32*)alloc((size_t)B * 16 * N * 4);
    u32* xnzs = (u32*)alloc((size_t)B * 16 * N * 4);
    u32* pls = (u32*)alloc((size_t)B * 64 * 4);
    u32* plnz = (u32*)alloc((size_t)B * 64 * 4);
    u32* l1s = (u32*)alloc((size_t)B * 16 * 4);
    u32* l1nz = (u32*)alloc((size_t)B * 16 * 4);
    float* pmax = (float*)alloc((size_t)B * 1024 * 4 * 4);
    float* psum = (float*)alloc((size_t)B * 1024 * 4 * 4);
    float* pooled = (float*)alloc((size_t)B * 2048 * 4);
    float* l2o = (float*)alloc((size_t)B * 256 * 4);
    if (off > ws_size) { sentinel(4.f); return; }

    pack_rows_kernel<<<1, 256, 0, stream>>>(w2, 64, 128, w2s_, w2nz_);
    pack_rows_kernel<<<2, 256, 0, stream>>>(w3, 128, 128, w3s_, w3nz_);
    pack_rows_kernel<<<8, 256, 0, stream>>>(w4, 256, 256, w4s_, w4nz_);
    pack_rows_kernel<<<64, 256, 0, stream>>>(w5, 1024, 512, w5s_, w5nz_);
    pack_rows_kernel<<<128, 256, 0, stream>>>(wl1, 512, 2048, wl1s_, wl1nz_);
    pack_rows_kernel<<<16, 256, 0, stream>>>(wl2, 256, 512, wl2s_, wl2nz_);

    dim3 gnb(N, B);
    dim3 gknn(N / 16, B);
    const int npt = (B * N + 255) / 256;
    // ---- layer 1 ----
    sq_np_kernel<3><<<npt, 256, 0, stream>>>(x0, 3, 0, sqb);
    transpose3_kernel<<<npt, 256, 0, stream>>>(x0, x0R);
    knn_radix4_kernel<3><<<gknn, 256, 0, stream>>>(x0, 3, 0, sqb, idxb);
    edgeconv1_kernel<3, 64>
        <<<gnb, 64, 0, stream>>>(x0R, idxb, w1, a1, s1, b1, p1, yA, xss, xnzs, 0);
    transpose_rm2cm_kernel<<<dim3(16, 1, B), 256, 0, stream>>>(yA, 64, xcat, 0);
    // ---- layer 2 ----
    sq_np_kernel<64><<<npt, 256, 0, stream>>>(xcat, 256, 0, sqb);
    knn_radix4_kernel<64><<<gknn, 256, 0, stream>>>(xcat, 256, 0, sqb, idxb);
    edgeconv_bin2_kernel<64, 64, true>
        <<<gnb, 64, 0, stream>>>(yA, idxb, w2s_, w2nz_, a2, s2, b2, p2, yB, xss, xnzs, 2);
    transpose_rm2cm_kernel<<<dim3(16, 1, B), 256, 0, stream>>>(yB, 64, xcat, 64);
    // ---- layer 3 ----
    sq_np_kernel<64><<<npt, 256, 0, stream>>>(xcat, 256, 64, sqb);
    knn_radix4_kernel<64><<<gknn, 256, 0, stream>>>(xcat, 256, 64, sqb, idxb);
    edgeconv_bin2_kernel<64, 128, true>
        <<<gnb, 128, 0, stream>>>(yB, idxb, w3s_, w3nz_, a3, s3, b3, p3, yA, xss, xnzs, 4);
    transpose_rm2cm_kernel<<<dim3(16, 2, B), 256, 0, stream>>>(yA, 128, xcat, 128);
    // ---- layer 4 ----
    sq_np_kernel<128><<<npt, 256, 0, stream>>>(xcat, 256, 128, sqb);
    knn_radix4_kernel<128><<<gknn, 256, 0, stream>>>(xcat, 256, 128, sqb, idxb);
    edgeconv_bin2_kernel<128, 256, false>
        <<<gnb, 256, 0, stream>>>(yA, idxb, w4s_, w4nz_, a4, s4, b4, p4, nullptr, xss, xnzs, 8);
    // ---- conv1d + pooling + heads ----
    conv1d_bin_pool_kernel<<<dim3(16, B), 256, 0, stream>>>(xss, xnzs, w5s_, w5nz_, a5, s5, b5,
                                                            p5, pmax, psum);
    pool_reduce_kernel<<<(B * 1024 + 255) / 256, 256, 0, stream>>>(pmax, psum, pooled);
    pack_pooled_kernel<<<(B * 64 + 255) / 256, 256, 0, stream>>>(pooled, pls, plnz);
    lin1_bin_kernel<<<dim3(2, B), 256, 0, stream>>>(pls, plnz, wl1s_, wl1nz_, al1, sl1, bl1, pl1,
                                                    l1s, l1nz);
    lin2_bin_kernel<<<B, 256, 0, stream>>>(l1s, l1nz, wl2s_, wl2nz_, al2, sl2, bl2, pl2, l2o);
    lin3_kernel<<<B, 64, 0, stream>>>(l2o, wl3, sl3, bl3, outp);
}

// Round 12
// 627.908 us; speedup vs baseline: 5.8586x; 1.0420x over previous
//
#include <hip/hip_runtime.h>
#include <math.h>

#define B 16
#define N 1024
#define KNB 20

typedef unsigned int u32;
typedef unsigned long long u64;

__device__ __forceinline__ float sgnf(float v) {
    return (v > 0.f) ? 1.f : ((v < 0.f) ? -1.f : 0.f);
}

__global__ __launch_bounds__(256) void sentinel_kernel(float* __restrict__ out, int n, float v) {
    int i = blockIdx.x * blockDim.x + threadIdx.x;
    if (i < n) out[i] = v;
}

// ---------------- np-exact sq (UNCHANGED arithmetic) ----------------

template <int C>
__global__ __launch_bounds__(256) void sq_np_kernel(const float* __restrict__ x, int Ctot, int c0,
                                                    float* __restrict__ sq) {
    int i = blockIdx.x * blockDim.x + threadIdx.x;
    if (i >= B * N) return;
    int b = i >> 10, n = i & (N - 1);
    const float* xb = x + ((size_t)b * Ctot + c0) * N + n;
    float res;
    if (C < 8) {
        float v0 = xb[0];
        res = __fmul_rn(v0, v0);
        for (int c = 1; c < C; ++c) {
            float v = xb[(size_t)c * N];
            res = __fadd_rn(res, __fmul_rn(v, v));
        }
    } else {
        float r[8];
#pragma unroll
        for (int j = 0; j < 8; ++j) {
            float v = xb[(size_t)j * N];
            r[j] = __fmul_rn(v, v);
        }
        for (int c = 8; c < C; c += 8) {
#pragma unroll
            for (int j = 0; j < 8; ++j) {
                float v = xb[(size_t)(c + j) * N];
                r[j] = __fadd_rn(r[j], __fmul_rn(v, v));
            }
        }
        res = __fadd_rn(__fadd_rn(__fadd_rn(r[0], r[1]), __fadd_rn(r[2], r[3])),
                        __fadd_rn(__fadd_rn(r[4], r[5]), __fadd_rn(r[6], r[7])));
    }
    sq[i] = res;
}

// ---------------- knn: 2-wave blocks, 4 points/wave (8/block); np-exact distances; ----------------
// top-20 SET via radix threshold + ballot compaction (ties -> lowest index, exact).
template <int C>
__global__ __launch_bounds__(128) void knn_radix4_kernel(const float* __restrict__ x, int Ctot,
                                                         int c0, const float* __restrict__ sq,
                                                         int* __restrict__ idxout) {
    const int b = blockIdx.y;
    const int tid = threadIdx.x, wave = tid >> 6, lane = tid & 63;
    const int nbase = blockIdx.x * 8;
    __shared__ float xn[C][8];
    const float* xb = x + ((size_t)b * Ctot + c0) * N;
    for (int t = tid; t < 8 * C; t += 128) {
        int pt = t & 7, c = t >> 3;
        xn[c][pt] = xb[(size_t)c * N + nbase + pt];
    }
    __syncthreads();
    float acc[4][16];
#pragma unroll
    for (int p = 0; p < 4; ++p)
#pragma unroll
        for (int j = 0; j < 16; ++j) acc[p][j] = 0.f;
    const int w4 = wave * 4;
    for (int c = 0; c < C; ++c) {
        const float* row = xb + (size_t)c * N + lane;
        float xv0 = xn[c][w4 + 0], xv1 = xn[c][w4 + 1];
        float xv2 = xn[c][w4 + 2], xv3 = xn[c][w4 + 3];
#pragma unroll
        for (int j = 0; j < 16; ++j) {
            float rv = row[j * 64];
            acc[0][j] = __fadd_rn(acc[0][j], __fmul_rn(xv0, rv));
            acc[1][j] = __fadd_rn(acc[1][j], __fmul_rn(xv1, rv));
            acc[2][j] = __fadd_rn(acc[2][j], __fmul_rn(xv2, rv));
            acc[3][j] = __fadd_rn(acc[3][j], __fmul_rn(xv3, rv));
        }
    }
    float sqm[16];
#pragma unroll
    for (int j = 0; j < 16; ++j) sqm[j] = sq[b * N + j * 64 + lane];
    const u64 ltmask = (1ull << lane) - 1ull;
#pragma unroll
    for (int p = 0; p < 4; ++p) {
        const int n = nbase + w4 + p;
        const float sqn = sq[b * N + n];
        u32 key[16];
#pragma unroll
        for (int j = 0; j < 16; ++j) {
            float d = __fsub_rn(__fsub_rn(__fmul_rn(2.f, acc[p][j]), sqn), sqm[j]);
            u32 bits = __float_as_uint(d);
            if ((bits << 1) == 0) bits = 0;  // canonicalize -0 -> +0
            key[j] = (bits & 0x80000000u) ? ~bits : (bits | 0x80000000u);
        }
        u32 T = 0;
        for (int bpos = 31; bpos >= 0; --bpos) {
            u32 cand = T | (1u << bpos);
            int cnt = 0;
#pragma unroll
            for (int j = 0; j < 16; ++j) cnt += __popcll(__ballot(key[j] >= cand));
            if (cnt >= KNB) T = cand;
        }
        int* out = idxout + ((size_t)b * N + n) * KNB;
        int base = 0;
#pragma unroll
        for (int j = 0; j < 16; ++j) {
            u64 m = __ballot(key[j] > T);
            if (key[j] > T) out[base + __popcll(m & ltmask)] = j * 64 + lane;
            base += __popcll(m);
        }
        const int R = KNB - base;  // ties, filled ascending index (j asc, lane asc)
        int eqb = 0;
#pragma unroll
        for (int j = 0; j < 16; ++j) {
            u64 m = __ballot(key[j] == T);
            int r = eqb + __popcll(m & ltmask);
            if (key[j] == T && r < R) out[base + r] = j * 64 + lane;
            eqb += __popcll(m);
        }
    }
}

// ---------------- x0 -> row-major copy ----------------

__global__ __launch_bounds__(256) void transpose3_kernel(const float* __restrict__ x,
                                                         float* __restrict__ xT) {
    int i = blockIdx.x * blockDim.x + threadIdx.x;
    if (i >= B * N) return;
    int b = i >> 10, n = i & (N - 1);
    xT[(size_t)i * 3 + 0] = x[((size_t)b * 3 + 0) * N + n];
    xT[(size_t)i * 3 + 1] = x[((size_t)b * 3 + 1) * N + n];
    xT[(size_t)i * 3 + 2] = x[((size_t)b * 3 + 2) * N + n];
}

// ---------------- row-major [B][N][CO] -> xcat col-major slice ----------------

__global__ __launch_bounds__(256) void transpose_rm2cm_kernel(const float* __restrict__ yR, int CO,
                                                              float* __restrict__ xcat, int c0) {
    const int nb = blockIdx.x * 64, cb = blockIdx.y * 64, b = blockIdx.z;
    const int tid = threadIdx.x;
    __shared__ float t[64][65];
    for (int i = tid; i < 64 * 64; i += 256) {
        int nn = i >> 6, cc = i & 63;
        t[nn][cc] = yR[((size_t)(b * N + nb + nn)) * CO + cb + cc];
    }
    __syncthreads();
    for (int i = tid; i < 64 * 64; i += 256) {
        int cc = i >> 6, nn = i & 63;
        xcat[((size_t)b * 256 + c0 + cb + cc) * N + nb + nn] = t[nn][cc];
    }
}

// ---------------- layer-1 edgeconv (np-exact) ----------------

template <int C, int COUT>
__global__ __launch_bounds__(COUT) void edgeconv1_kernel(
    const float* __restrict__ xR, const int* __restrict__ idx, const float* __restrict__ W,
    const float* __restrict__ aa, const float* __restrict__ ssc, const float* __restrict__ bbi,
    const float* __restrict__ pp, float* __restrict__ yR, u32* __restrict__ xss,
    u32* __restrict__ xnzs, int woff) {
    const int b = blockIdx.y, n = blockIdx.x, tid = threadIdx.x;
    __shared__ float ctr_raw[C];
    __shared__ float df[C][KNB];
    __shared__ int ids[KNB];
    const float* xb = xR + (size_t)b * N * C;
    if (tid < KNB) ids[tid] = idx[((size_t)b * N + n) * KNB + tid];
    if (tid < C) ctr_raw[tid] = xb[(size_t)n * C + tid];
    __syncthreads();
    for (int t = tid; t < C * KNB; t += COUT) {
        int c = t / KNB, k = t - c * KNB;
        df[c][k] = __fsub_rn(xb[(size_t)ids[k] * C + c], ctr_raw[c]);
    }
    __syncthreads();
    const int o = tid;
    const float* wrow = W + (size_t)o * (2 * C);
    const float as = __fmul_rn(aa[o], ssc[o]);
    const float bo = bbi[o], po = pp[o];
    float best = -3.4e38f;
    float wd[C], wc[C];
    for (int c = 0; c < C; ++c) { wd[c] = sgnf(wrow[c]); wc[c] = sgnf(wrow[C + c]); }
    for (int k = 0; k < KNB; ++k) {
        float acc = 0.f;
        for (int c = 0; c < C; ++c) acc = __fadd_rn(acc, __fmul_rn(df[c][k], wd[c]));
        for (int c = 0; c < C; ++c) acc = __fadd_rn(acc, __fmul_rn(ctr_raw[c], wc[c]));
        float y = __fadd_rn(__fmul_rn(acc, as), bo);
        y = y > 0.f ? y : __fmul_rn(po, y);
        best = fmaxf(best, y);
    }
    yR[((size_t)b * N + n) * COUT + o] = best;
    u64 bs = __ballot(best < 0.f);
    u64 bnz = __ballot(best != 0.f);
    if ((tid & 63) == 0) {
        int w = woff + (tid >> 5);
        xss[(size_t)(b * 16 + w) * N + n] = (u32)bs;
        xss[(size_t)(b * 16 + w + 1) * N + n] = (u32)(bs >> 32);
        xnzs[(size_t)(b * 16 + w) * N + n] = (u32)bnz;
        xnzs[(size_t)(b * 16 + w + 1) * N + n] = (u32)(bnz >> 32);
    }
}

// ---------------- ternary weight / vector pack ----------------

__global__ __launch_bounds__(256) void pack_rows_kernel(const float* __restrict__ src, int rows,
                                                        int cols, u32* __restrict__ s,
                                                        u32* __restrict__ nz) {
    int i = blockIdx.x * blockDim.x + threadIdx.x;
    int wpr = cols >> 5;
    if (i >= rows * wpr) return;
    int r = i / wpr, w = i - r * wpr;
    const float* p = src + (size_t)r * cols + (size_t)w * 32;
    u32 sb = 0, nb = 0;
    for (int j = 0; j < 32; ++j) {
        float v = p[j];
        if (v < 0.f) sb |= (1u << j);
        if (v != 0.f) nb |= (1u << j);
    }
    s[i] = sb;
    nz[i] = nb;
}

// ---------------- binarized edgeconv (UNCHANGED from R10) ----------------

template <int C, int COUT, bool WRITEF>
__global__ __launch_bounds__(COUT) void edgeconv_bin2_kernel(
    const float* __restrict__ xR, const int* __restrict__ idx, const u32* __restrict__ wsm,
    const u32* __restrict__ wnzm, const float* __restrict__ aa, const float* __restrict__ ssc,
    const float* __restrict__ bbi, const float* __restrict__ pp, float* __restrict__ yR,
    u32* __restrict__ xss, u32* __restrict__ xnzs, int woff) {
    constexpr int W = C / 32;
    const int b = blockIdx.y, n = blockIdx.x, tid = threadIdx.x;
    __shared__ float ctr_raw[C];
    __shared__ int ids[KNB];
    __shared__ u32 ctr_s[W], ctr_nz[W];
    __shared__ u32 dfs[KNB][W], dfnz[KNB][W];
    const float* xb = xR + (size_t)b * N * C;
    if (tid < KNB) ids[tid] = idx[((size_t)b * N + n) * KNB + tid];
    if (tid < C) {
        float v = xb[(size_t)n * C + tid];
        ctr_raw[tid] = v;
        u64 bs = __ballot(v < 0.f);
        u64 bnz = __ballot(v != 0.f);
        if ((tid & 63) == 0) {
            int wb = tid >> 5;
            ctr_s[wb] = (u32)bs;       ctr_s[wb + 1] = (u32)(bs >> 32);
            ctr_nz[wb] = (u32)bnz;     ctr_nz[wb + 1] = (u32)(bnz >> 32);
        }
    }
    __syncthreads();
    for (int t = tid; t < KNB * C; t += COUT) {
        int k = t / C, c = t - k * C;
        float v = __fsub_rn(xb[(size_t)ids[k] * C + c], ctr_raw[c]);
        u64 bs = __ballot(v < 0.f);
        u64 bnz = __ballot(v != 0.f);
        if ((c & 63) == 0) {
            int wb = c >> 5;
            dfs[k][wb] = (u32)bs;      dfs[k][wb + 1] = (u32)(bs >> 32);
            dfnz[k][wb] = (u32)bnz;    dfnz[k][wb + 1] = (u32)(bnz >> 32);
        }
    }
    __syncthreads();
    const int o = tid;
    const u32* wsrow = wsm + (size_t)o * 2 * W;
    const u32* wnzrow = wnzm + (size_t)o * 2 * W;
    u32 wds[W], wdnz[W], wcs[W], wcnz[W];
#pragma unroll
    for (int w = 0; w < W; ++w) {
        wds[w] = wsrow[w];      wcs[w] = wsrow[W + w];
        wdnz[w] = wnzrow[w];    wcnz[w] = wnzrow[W + w];
    }
    int cdot = 0;
#pragma unroll
    for (int w = 0; w < W; ++w) {
        u32 nzb = ctr_nz[w] & wcnz[w];
        u32 neg = (ctr_s[w] ^ wcs[w]) & nzb;
        cdot += __popc(nzb) - 2 * __popc(neg);
    }
    const float as = __fmul_rn(aa[o], ssc[o]);
    const float bo = bbi[o], po = pp[o];
    float best = -3.4e38f;
    for (int k = 0; k < KNB; ++k) {
        int dot = cdot;
#pragma unroll
        for (int w = 0; w < W; ++w) {
            u32 nzb = dfnz[k][w] & wdnz[w];
            u32 neg = (dfs[k][w] ^ wds[w]) & nzb;
            dot += __popc(nzb) - 2 * __popc(neg);
        }
        float y = __fadd_rn(__fmul_rn((float)dot, as), bo);
        y = y > 0.f ? y : __fmul_rn(po, y);
        best = fmaxf(best, y);
    }
    if (WRITEF) yR[((size_t)b * N + n) * COUT + o] = best;
    u64 bs = __ballot(best < 0.f);
    u64 bnz = __ballot(best != 0.f);
    if ((tid & 63) == 0) {
        int w = woff + (tid >> 5);
        xss[(size_t)(b * 16 + w) * N + n] = (u32)bs;
        xss[(size_t)(b * 16 + w + 1) * N + n] = (u32)(bs >> 32);
        xnzs[(size_t)(b * 16 + w) * N + n] = (u32)bnz;
        xnzs[(size_t)(b * 16 + w + 1) * N + n] = (u32)(bnz >> 32);
    }
}

// ---------------- conv1d bitplane popcount + fused pooling: 16 n-chunks of 64 ----------------

__global__ __launch_bounds__(256) void conv1d_bin_pool_kernel(
    const u32* __restrict__ xs, const u32* __restrict__ xnz, const u32* __restrict__ w5s,
    const u32* __restrict__ w5nz, const float* __restrict__ aa, const float* __restrict__ ssc,
    const float* __restrict__ bbi, const float* __restrict__ pp, float* __restrict__ pmax,
    float* __restrict__ psum) {
    const int b = blockIdx.y;
    const int otile = blockIdx.x & 3;
    const int nq = blockIdx.x >> 2;  // 0..15
    const int tid = threadIdx.x;
    const int o = otile * 256 + tid;
    __shared__ u32 shs[64][21];
    __shared__ u32 shnz[64][21];
    u32 ws[16], wnz[16];
#pragma unroll
    for (int w = 0; w < 16; ++w) {
        ws[w] = w5s[(size_t)o * 16 + w];
        wnz[w] = w5nz[(size_t)o * 16 + w];
    }
    const int nbase = nq * 64;
    for (int t = tid; t < 16 * 64; t += 256) {
        int w = t >> 6, nl = t & 63;
        shs[nl][w] = xs[((size_t)b * 16 + w) * N + nbase + nl];
        shnz[nl][w] = xnz[((size_t)b * 16 + w) * N + nbase + nl];
    }
    __syncthreads();
    const float as = __fmul_rn(aa[o], ssc[o]);
    const float bo = bbi[o], po = pp[o];
    float m = -3.4e38f, sum = 0.f;
    for (int nl = 0; nl < 64; ++nl) {
        int dot = 0;
#pragma unroll
        for (int w = 0; w < 16; ++w) {
            u32 nzb = shnz[nl][w] & wnz[w];
            u32 neg = (shs[nl][w] ^ ws[w]) & nzb;
            dot += __popc(nzb) - 2 * __popc(neg);
        }
        float y = __fadd_rn(__fmul_rn((float)dot, as), bo);
        y = y > 0.f ? y : __fmul_rn(po, y);
        m = fmaxf(m, y);
        sum = __fadd_rn(sum, y);  // exact: quarter-integers
    }
    pmax[((size_t)b * 1024 + o) * 16 + nq] = m;
    psum[((size_t)b * 1024 + o) * 16 + nq] = sum;
}

__global__ __launch_bounds__(256) void pool_reduce_kernel(const float* __restrict__ pmax,
                                                          const float* __restrict__ psum,
                                                          float* __restrict__ pooled) {
    int i = blockIdx.x * blockDim.x + threadIdx.x;
    if (i >= B * 1024) return;
    int b = i >> 10, o = i & 1023;
    const float* pm = pmax + (size_t)i * 16;
    const float* ps = psum + (size_t)i * 16;
    float m = -3.4e38f, s = 0.f;
    for (int t = 0; t < 16; ++t) { m = fmaxf(m, pm[t]); s = __fadd_rn(s, ps[t]); }
    pooled[(size_t)b * 2048 + o] = m;
    pooled[(size_t)b * 2048 + 1024 + o] = __fmul_rn(s, (1.f / 1024.f));
}

// pack pooled (B x 2048) into ternary bitplanes: B x 64 words
__global__ __launch_bounds__(256) void pack_pooled_kernel(const float* __restrict__ pooled,
                                                          u32* __restrict__ s,
                                                          u32* __restrict__ nz) {
    int i = blockIdx.x * blockDim.x + threadIdx.x;
    if (i >= B * 64) return;
    const float* p = pooled + (size_t)i * 32;
    u32 sb = 0, nb = 0;
    for (int j = 0; j < 32; ++j) {
        float v = p[j];
        if (v < 0.f) sb |= (1u << j);
        if (v != 0.f) nb |= (1u << j);
    }
    s[i] = sb;
    nz[i] = nb;
}

// ---------------- bitpacked lin1 / lin2 / lin3 (UNCHANGED) ----------------

__global__ __launch_bounds__(256) void lin1_bin_kernel(
    const u32* __restrict__ xs, const u32* __restrict__ xnz, const u32* __restrict__ wls,
    const u32* __restrict__ wlnz, const float* __restrict__ aa, const float* __restrict__ ssc,
    const float* __restrict__ bbi, const float* __restrict__ pp, u32* __restrict__ l1s,
    u32* __restrict__ l1nz) {
    const int b = blockIdx.y, otile = blockIdx.x, tid = threadIdx.x;
    const int o = otile * 256 + tid;
    __shared__ u32 sxs[64], sxnz[64];
    if (tid < 64) { sxs[tid] = xs[b * 64 + tid]; sxnz[tid] = xnz[b * 64 + tid]; }
    __syncthreads();
    const u32* wsr = wls + (size_t)o * 64;
    const u32* wnzr = wlnz + (size_t)o * 64;
    int dot = 0;
#pragma unroll
    for (int w = 0; w < 64; ++w) {
        u32 nzb = sxnz[w] & wnzr[w];
        u32 neg = (sxs[w] ^ wsr[w]) & nzb;
        dot += __popc(nzb) - 2 * __popc(neg);
    }
    float y = __fadd_rn(__fmul_rn((float)dot, __fmul_rn(aa[o], ssc[o])), bbi[o]);
    y = y > 0.f ? y : __fmul_rn(pp[o], y);
    u64 bs = __ballot(y < 0.f);
    u64 bnz = __ballot(y != 0.f);
    if ((tid & 63) == 0) {
        int w = otile * 8 + (tid >> 5);
        l1s[b * 16 + w] = (u32)bs;       l1s[b * 16 + w + 1] = (u32)(bs >> 32);
        l1nz[b * 16 + w] = (u32)bnz;     l1nz[b * 16 + w + 1] = (u32)(bnz >> 32);
    }
}

__global__ __launch_bounds__(256) void lin2_bin_kernel(
    const u32* __restrict__ xs, const u32* __restrict__ xnz, const u32* __restrict__ wls,
    const u32* __restrict__ wlnz, const float* __restrict__ aa, const float* __restrict__ ssc,
    const float* __restrict__ bbi, const float* __restrict__ pp, float* __restrict__ out) {
    const int b = blockIdx.x, o = threadIdx.x;
    __shared__ u32 sxs[16], sxnz[16];
    if (o < 16) { sxs[o] = xs[b * 16 + o]; sxnz[o] = xnz[b * 16 + o]; }
    __syncthreads();
    const u32* wsr = wls + (size_t)o * 16;
    const u32* wnzr = wlnz + (size_t)o * 16;
    int dot = 0;
#pragma unroll
    for (int w = 0; w < 16; ++w) {
        u32 nzb = sxnz[w] & wnzr[w];
        u32 neg = (sxs[w] ^ wsr[w]) & nzb;
        dot += __popc(nzb) - 2 * __popc(neg);
    }
    float y = __fadd_rn(__fmul_rn((float)dot, __fmul_rn(aa[o], ssc[o])), bbi[o]);
    out[b * 256 + o] = y > 0.f ? y : __fmul_rn(pp[o], y);
}

__global__ __launch_bounds__(64) void lin3_kernel(const float* __restrict__ xin,
                                                  const float* __restrict__ W,
                                                  const float* __restrict__ ssc,
                                                  const float* __restrict__ bbi,
                                                  float* __restrict__ out) {
    int b = blockIdx.x, j = threadIdx.x;
    if (j >= 40) return;
    const float* wrow = W + j * 256;
    const float* xb = xin + b * 256;
    double acc = 0.0;
    for (int c = 0; c < 256; ++c) acc = fma((double)xb[c], (double)wrow[c], acc);
    out[b * 40 + j] = __fadd_rn(__fmul_rn((float)acc, ssc[j]), bbi[j]);
}

extern "C" void kernel_launch(void* const* d_in, const int* in_sizes, int n_in, void* d_out,
                              int out_size, void* d_ws, size_t ws_size, hipStream_t stream) {
    float* outp = (float*)d_out;
    auto sentinel = [&](float code) {
        sentinel_kernel<<<(640 + 255) / 256, 256, 0, stream>>>(outp, 640, code * 1.0e6f);
    };
    if (n_in != 39) { sentinel(1.f); return; }
    static const int expect[39] = {
        16 * 3 * 1024,
        64 * 6, 64, 64, 64, 64,
        64 * 128, 64, 64, 64, 64,
        128 * 128, 128, 128, 128, 128,
        256 * 256, 256, 256, 256, 256,
        1024 * 512, 1024, 1024, 1024, 1024,
        512 * 2048, 512, 512, 512, 512,
        256 * 512, 256, 256, 256, 256,
        40 * 256, 40, 40
    };
    for (int i = 0; i < 39; ++i)
        if (in_sizes[i] != expect[i]) { sentinel(2.f); return; }
    if (out_size != 640) { sentinel(3.f); return; }

    const float* x0 = (const float*)d_in[0];
    const float *w1 = (const float*)d_in[1], *a1 = (const float*)d_in[2],
                *s1 = (const float*)d_in[3], *b1 = (const float*)d_in[4],
                *p1 = (const float*)d_in[5];
    const float *a2 = (const float*)d_in[7], *s2 = (const float*)d_in[8],
                *b2 = (const float*)d_in[9], *p2 = (const float*)d_in[10];
    const float *a3 = (const float*)d_in[12], *s3 = (const float*)d_in[13],
                *b3 = (const float*)d_in[14], *p3 = (const float*)d_in[15];
    const float *a4 = (const float*)d_in[17], *s4 = (const float*)d_in[18],
                *b4 = (const float*)d_in[19], *p4 = (const float*)d_in[20];
    const float *a5 = (const float*)d_in[22], *s5 = (const float*)d_in[23],
                *b5 = (const float*)d_in[24], *p5 = (const float*)d_in[25];
    const float *w2 = (const float*)d_in[6], *w3 = (const float*)d_in[11],
                *w4 = (const float*)d_in[16], *w5 = (const float*)d_in[21];
    const float *wl1 = (const float*)d_in[26], *al1 = (const float*)d_in[27],
                *sl1 = (const float*)d_in[28], *bl1 = (const float*)d_in[29],
                *pl1 = (const float*)d_in[30];
    const float *wl2 = (const float*)d_in[31], *al2 = (const float*)d_in[32],
                *sl2 = (const float*)d_in[33], *bl2 = (const float*)d_in[34],
                *pl2 = (const float*)d_in[35];
    const float *wl3 = (const float*)d_in[36], *sl3 = (const float*)d_in[37],
                *bl3 = (const float*)d_in[38];

    char* ws = (char*)d_ws;
    size_t off = 0;
    auto alloc = [&](size_t bytes) -> void* {
        void* p = ws + off;
        off += (bytes + 255) & ~(size_t)255;
        return p;
    };
    float* xcat = (float*)alloc((size_t)B * 256 * N * 4);
    float* yA = (float*)alloc((size_t)B * N * 128 * 4);
    float* yB = (float*)alloc((size_t)B * N * 64 * 4);
    float* x0R = (float*)alloc((size_t)B * N * 3 * 4);
    int* idxb = (int*)alloc((size_t)B * N * KNB * 4);
    float* sqb = (float*)alloc((size_t)B * N * 4);
    u32* w2s_ = (u32*)alloc(64 * 4 * 4);     u32* w2nz_ = (u32*)alloc(64 * 4 * 4);
    u32* w3s_ = (u32*)alloc(128 * 4 * 4);    u32* w3nz_ = (u32*)alloc(128 * 4 * 4);
    u32* w4s_ = (u32*)alloc(256 * 8 * 4);    u32* w4nz_ = (u32*)alloc(256 * 8 * 4);
    u32* w5s_ = (u32*)alloc(1024 * 16 * 4);  u32* w5nz_ = (u32*)alloc(1024 * 16 * 4);
    u32* wl1s_ = (u32*)alloc(512 * 64 * 4);  u32* wl1nz_ = (u32*)alloc(512 * 64 * 4);
    u32* wl2s_ = (u32*)alloc(256 * 16 * 4);  u32* wl2nz_ = (u32*)alloc(256 * 16 * 4);
    u32* xss = (u32*)alloc((size_t)B * 16 * N * 4);
    u32* xnzs = (u32*)alloc((size_t)B * 16 * N * 4);
    u32* pls = (u32*)alloc((size_t)B * 64 * 4);
    u32* plnz = (u32*)alloc((size_t)B * 64 * 4);
    u32* l1s = (u32*)alloc((size_t)B * 16 * 4);
    u32* l1nz = (u32*)alloc((size_t)B * 16 * 4);
    float* pmax = (float*)alloc((size_t)B * 1024 * 16 * 4);
    float* psum = (float*)alloc((size_t)B * 1024 * 16 * 4);
    float* pooled = (float*)alloc((size_t)B * 2048 * 4);
    float* l2o = (float*)alloc((size_t)B * 256 * 4);
    if (off > ws_size) { sentinel(4.f); return; }

    pack_rows_kernel<<<1, 256, 0, stream>>>(w2, 64, 128, w2s_, w2nz_);
    pack_rows_kernel<<<2, 256, 0, stream>>>(w3, 128, 128, w3s_, w3nz_);
    pack_rows_kernel<<<8, 256, 0, stream>>>(w4, 256, 256, w4s_, w4nz_);
    pack_rows_kernel<<<64, 256, 0, stream>>>(w5, 1024, 512, w5s_, w5nz_);
    pack_rows_kernel<<<128, 256, 0, stream>>>(wl1, 512, 2048, wl1s_, wl1nz_);
    pack_rows_kernel<<<16, 256, 0, stream>>>(wl2, 256, 512, wl2s_, wl2nz_);

    dim3 gnb(N, B);
    dim3 gknn(N / 8, B);
    const int npt = (B * N + 255) / 256;
    // ---- layer 1 ----
    sq_np_kernel<3><<<npt, 256, 0, stream>>>(x0, 3, 0, sqb);
    transpose3_kernel<<<npt, 256, 0, stream>>>(x0, x0R);
    knn_radix4_kernel<3><<<gknn, 128, 0, stream>>>(x0, 3, 0, sqb, idxb);
    edgeconv1_kernel<3, 64>
        <<<gnb, 64, 0, stream>>>(x0R, idxb, w1, a1, s1, b1, p1, yA, xss, xnzs, 0);
    transpose_rm2cm_kernel<<<dim3(16, 1, B), 256, 0, stream>>>(yA, 64, xcat, 0);
    // ---- layer 2 ----
    sq_np_kernel<64><<<npt, 256, 0, stream>>>(xcat, 256, 0, sqb);
    knn_radix4_kernel<64><<<gknn, 128, 0, stream>>>(xcat, 256, 0, sqb, idxb);
    edgeconv_bin2_kernel<64, 64, true>
        <<<gnb, 64, 0, stream>>>(yA, idxb, w2s_, w2nz_, a2, s2, b2, p2, yB, xss, xnzs, 2);
    transpose_rm2cm_kernel<<<dim3(16, 1, B), 256, 0, stream>>>(yB, 64, xcat, 64);
    // ---- layer 3 ----
    sq_np_kernel<64><<<npt, 256, 0, stream>>>(xcat, 256, 64, sqb);
    knn_radix4_kernel<64><<<gknn, 128, 0, stream>>>(xcat, 256, 64, sqb, idxb);
    edgeconv_bin2_kernel<64, 128, true>
        <<<gnb, 128, 0, stream>>>(yB, idxb, w3s_, w3nz_, a3, s3, b3, p3, yA, xss, xnzs, 4);
    transpose_rm2cm_kernel<<<dim3(16, 2, B), 256, 0, stream>>>(yA, 128, xcat, 128);
    // ---- layer 4 ----
    sq_np_kernel<128><<<npt, 256, 0, stream>>>(xcat, 256, 128, sqb);
    knn_radix4_kernel<128><<<gknn, 128, 0, stream>>>(xcat, 256, 128, sqb, idxb);
    edgeconv_bin2_kernel<128, 256, false>
        <<<gnb, 256, 0, stream>>>(yA, idxb, w4s_, w4nz_, a4, s4, b4, p4, nullptr, xss, xnzs, 8);
    // ---- conv1d + pooling + heads ----
    conv1d_bin_pool_kernel<<<dim3(64, B), 256, 0, stream>>>(xss, xnzs, w5s_, w5nz_, a5, s5, b5,
                                                            p5, pmax, psum);
    pool_reduce_kernel<<<(B * 1024 + 255) / 256, 256, 0, stream>>>(pmax, psum, pooled);
    pack_pooled_kernel<<<(B * 64 + 255) / 256, 256, 0, stream>>>(pooled, pls, plnz);
    lin1_bin_kernel<<<dim3(2, B), 256, 0, stream>>>(pls, plnz, wl1s_, wl1nz_, al1, sl1, bl1, pl1,
                                                    l1s, l1nz);
    lin2_bin_kernel<<<B, 256, 0, stream>>>(l1s, l1nz, wl2s_, wl2nz_, al2, sl2, bl2, pl2, l2o);
    lin3_kernel<<<B, 64, 0, stream>>>(l2o, wl3, sl3, bl3, outp);
}